// Round 1
// baseline (10286.401 us; speedup 1.0000x reference)
//
#include <hip/hip_runtime.h>
#include <math.h>

// ---------------- problem constants ----------------
#define B_   64
#define C_   256
#define T_   128
#define J_   17
#define THW  2176      // T_*J_
#define HC   43        // conv out H  : floor((128+2-3)/3)+1
#define WC   6         // conv out W  : floor((17+2-3)/3)+1
#define P_   258       // HC*WC
#define NH_  8
#define HD_  32
#define HID_ 1024
#define KCONV 2304     // 256*9

// ---------------- ws layout (floats) ----------------
// c_n1[512] c_qbn[1536] c_n2[512] c_b1[2048] c_b2[512]
// wt_conv[2304*768] projt[256*256] w1t[256*1024] w2t[1024*256]
// q[64*8*258*32] k[..] v[..] attn_out[..]     total ~19.27M floats = 77.1MB

// ---------------- precompute kernels ----------------
__global__ void bn_pre(const float* __restrict__ g, const float* __restrict__ b,
                       const float* __restrict__ m, const float* __restrict__ v,
                       float* __restrict__ o, int n)
{
  for (int i = blockIdx.x * blockDim.x + threadIdx.x; i < n; i += gridDim.x * blockDim.x) {
    float inv = g[i] / sqrtf(v[i] + 1e-5f);
    o[i]     = inv;
    o[n + i] = b[i] - m[i] * inv;
  }
}

// qkv_w (768,256,3,3) flat = co*2304 + (ci*9+kh*3+kw)  ->  wt[k*768 + co]
__global__ void tr_conv(const float* __restrict__ w, float* __restrict__ wt)
{
  int i = blockIdx.x * 256 + threadIdx.x;
  if (i < 768 * KCONV) {
    int co = i / KCONV, k = i - co * KCONV;
    wt[k * 768 + co] = w[i];
  }
}

// w (R,C) row-major -> wt[c*R + r]
__global__ void tr_mat(const float* __restrict__ w, float* __restrict__ wt, int R, int C)
{
  int i = blockIdx.x * 256 + threadIdx.x;
  if (i < R * C) {
    int r = i / C, c = i - r * C;
    wt[c * R + r] = w[i];
  }
}

// ---------------- conv qkv: implicit GEMM M=768 K=2304 N=16512 ----------------
// block: 256 thr = 4 groups x 64 cols; grid (258 colblocks, 3 mblocks)
__global__ __launch_bounds__(256) void conv_qkv(
    const float* __restrict__ x, const float* __restrict__ wt,
    const float* __restrict__ cn1, const float* __restrict__ cqbn,
    float* __restrict__ qo, float* __restrict__ ko, float* __restrict__ vo)
{
  __shared__ float gl[64][257];
  const int tid  = threadIdx.x;
  const int lane = tid & 63;
  const int g    = __builtin_amdgcn_readfirstlane(tid >> 6);
  const int col0 = blockIdx.x * 64;
  const int mb   = blockIdx.y;

  float acc[64];
#pragma unroll
  for (int i = 0; i < 64; ++i) acc[i] = 0.f;

  for (int ch = 0; ch < 9; ++ch) {
    __syncthreads();
    for (int e = tid; e < 64 * 256; e += 256) {
      int kk = e >> 6, col = e & 63;
      int gcol = col0 + col;
      int b = gcol / P_, p = gcol - b * P_;
      int oh = p / WC, ow = p - oh * WC;
      int k = ch * 256 + kk;
      int ci = k / 9; int rem = k - ci * 9;
      int kh = rem / 3, kw = rem - kh * 3;
      int ir = 3 * oh - 1 + kh;
      int ic = 3 * ow - 1 + kw;
      float val = 0.f;
      if ((unsigned)ir < (unsigned)T_ && (unsigned)ic < (unsigned)J_)
        val = x[((b * C_ + ci) * T_ + ir) * J_ + ic] * cn1[ci] + cn1[C_ + ci];
      gl[col][kk] = val;
    }
    __syncthreads();
#pragma unroll 1
    for (int kk = 0; kk < 256; ++kk) {
      float r = gl[lane][kk];
      const float* wr = wt + (ch * 256 + kk) * 768 + mb * 256 + g * 64;  // uniform -> s_load
#pragma unroll
      for (int k2 = 0; k2 < 64; ++k2) acc[k2] = fmaf(wr[k2], r, acc[k2]);
    }
  }

  int gcol = col0 + lane;
  int b = gcol / P_, p = gcol - b * P_;
#pragma unroll
  for (int k2 = 0; k2 < 64; ++k2) {
    int co = mb * 256 + g * 64 + k2;
    float vb = acc[k2] * cqbn[co] + cqbn[768 + co];
    float ge = 0.5f * vb * (1.f + erff(vb * 0.70710678118654752f));
    int which = co >> 8, rr = co & 255, head = rr >> 5, d = rr & 31;
    int idx = ((b * NH_ + head) * P_ + p) * HD_ + d;
    if (which == 0)      qo[idx] = ge * 0.176776695296636881f;  // fold 1/sqrt(32)
    else if (which == 1) ko[idx] = ge;
    else                 vo[idx] = ge;
  }
}

// ---------------- attention: one block per (b,h) ----------------
__global__ __launch_bounds__(256) void attn_k(
    const float* __restrict__ q, const float* __restrict__ k,
    const float* __restrict__ v, float* __restrict__ o)
{
  __shared__ float Kl[P_][33];
  __shared__ float Vl[P_][33];
  __shared__ float pb[4][264];
  const int bh = blockIdx.x;
  const int tid = threadIdx.x, lane = tid & 63, w = tid >> 6;
  const float* kb = k + bh * (P_ * HD_);
  const float* vb = v + bh * (P_ * HD_);
  for (int e = tid; e < P_ * HD_; e += 256) {
    Kl[e >> 5][e & 31] = kb[e];
    Vl[e >> 5][e & 31] = vb[e];
  }
  __syncthreads();
  for (int r = w; r < P_; r += 4) {
    const float4* qr = (const float4*)(q + (bh * P_ + r) * HD_);
    float qv[32];
#pragma unroll
    for (int i = 0; i < 8; ++i) {
      float4 t = qr[i];
      qv[4*i] = t.x; qv[4*i+1] = t.y; qv[4*i+2] = t.z; qv[4*i+3] = t.w;
    }
    float s[5];
    float m = -1e30f;
#pragma unroll
    for (int i = 0; i < 5; ++i) {
      int p = lane + (i << 6);
      float a = -1e30f;
      if (p < P_) {
        a = 0.f;
#pragma unroll
        for (int d = 0; d < 32; ++d) a = fmaf(qv[d], Kl[p][d], a);
      }
      s[i] = a;
      m = fmaxf(m, a);
    }
#pragma unroll
    for (int off = 32; off > 0; off >>= 1) m = fmaxf(m, __shfl_xor(m, off));
    float sum = 0.f;
#pragma unroll
    for (int i = 0; i < 5; ++i) {
      int p = lane + (i << 6);
      float e = (p < P_) ? expf(s[i] - m) : 0.f;
      s[i] = e;
      sum += e;
    }
#pragma unroll
    for (int off = 32; off > 0; off >>= 1) sum += __shfl_xor(sum, off);
    float rinv = 1.f / sum;
#pragma unroll
    for (int i = 0; i < 5; ++i) {
      int p = lane + (i << 6);
      if (p < P_) pb[w][p] = s[i] * rinv;
    }
    __builtin_amdgcn_wave_barrier();   // same-wave LDS write->read; pin order
    int half = lane >> 5, d = lane & 31;
    float a = 0.f;
    int p0 = half * 129;
#pragma unroll 1
    for (int p = p0; p < p0 + 129; ++p) a = fmaf(pb[w][p], Vl[p][d], a);
    a += __shfl_xor(a, 32);
    if (lane < 32) o[(bh * P_ + r) * HD_ + d] = a;
    __builtin_amdgcn_wave_barrier();
  }
}

// ---------------- bilinear resize + 1x1 proj + residual -> x' in d_out ----------------
__global__ __launch_bounds__(256) void proj_resize(
    const float* __restrict__ ao, const float* __restrict__ projt,
    const float* __restrict__ projb, const float* __restrict__ x,
    float* __restrict__ out)
{
  __shared__ float R[64][257];
  __shared__ float cw[64][4];
  __shared__ int   cix[64][4];
  const int tid = threadIdx.x, lane = tid & 63;
  const int g   = __builtin_amdgcn_readfirstlane(tid >> 6);
  const int blk = blockIdx.x;
  const int b   = blk / 34;
  const int s0  = (blk - b * 34) * 64;
  if (tid < 64) {
    int s = s0 + tid;
    int t = s / J_, j = s - t * J_;
    float ft = fmaxf((t + 0.5f) * ((float)HC / (float)T_) - 0.5f, 0.f);
    float fj = fmaxf((j + 0.5f) * ((float)WC / (float)J_) - 0.5f, 0.f);
    int i0 = (int)ft; if (i0 > HC - 1) i0 = HC - 1;
    int j0 = (int)fj; if (j0 > WC - 1) j0 = WC - 1;
    int i1 = min(i0 + 1, HC - 1);
    int j1 = min(j0 + 1, WC - 1);
    float wt_ = ft - (float)i0, wj_ = fj - (float)j0;
    cix[tid][0] = i0 * WC + j0; cix[tid][1] = i0 * WC + j1;
    cix[tid][2] = i1 * WC + j0; cix[tid][3] = i1 * WC + j1;
    cw[tid][0] = (1.f - wt_) * (1.f - wj_); cw[tid][1] = (1.f - wt_) * wj_;
    cw[tid][2] = wt_ * (1.f - wj_);         cw[tid][3] = wt_ * wj_;
  }
  __syncthreads();
  for (int e = tid; e < 64 * 256; e += 256) {
    int ci = e >> 6, col = e & 63;
    int head = ci >> 5, d = ci & 31;
    const float* A = ao + (b * NH_ + head) * (P_ * HD_) + d;
    R[col][ci] = cw[col][0] * A[cix[col][0] * HD_] + cw[col][1] * A[cix[col][1] * HD_]
               + cw[col][2] * A[cix[col][2] * HD_] + cw[col][3] * A[cix[col][3] * HD_];
  }
  __syncthreads();
  float acc[64];
#pragma unroll
  for (int i = 0; i < 64; ++i) acc[i] = 0.f;
#pragma unroll 1
  for (int ci = 0; ci < 256; ++ci) {
    float r = R[lane][ci];
    const float* wr = projt + ci * 256 + g * 64;   // uniform -> s_load
#pragma unroll
    for (int k2 = 0; k2 < 64; ++k2) acc[k2] = fmaf(wr[k2], r, acc[k2]);
  }
  int s = s0 + lane;
#pragma unroll
  for (int k2 = 0; k2 < 64; ++k2) {
    int co = g * 64 + k2;
    int xi = (b * C_ + co) * THW + s;
    out[xi] = x[xi] + projb[co] + acc[k2];
  }
}

// ---------------- fused MLP (fc1+bn+gelu+fc2+bn+residual), in-place on d_out ----------------
__global__ __launch_bounds__(512) void mlp_k(
    const float* __restrict__ xp, const float* __restrict__ w1t,
    const float* __restrict__ fc1b, const float* __restrict__ w2t,
    const float* __restrict__ fc2b, const float* __restrict__ cn2,
    const float* __restrict__ cb1, const float* __restrict__ cb2,
    float* __restrict__ out)
{
  __shared__ float U[64][257];
  __shared__ float Hb[64][133];
  const int tid = threadIdx.x, lane = tid & 63;
  const int g   = __builtin_amdgcn_readfirstlane(tid >> 6);   // 0..7
  const int blk = blockIdx.x;
  const int b   = blk / 34;
  const int s0  = (blk - b * 34) * 64;
  for (int e = tid; e < 64 * 256; e += 512) {
    int ci = e >> 6, col = e & 63;
    float xv = xp[(b * C_ + ci) * THW + s0 + col];
    U[col][ci] = xv * cn2[ci] + cn2[C_ + ci];
  }
  __syncthreads();
  float acc2[32];
#pragma unroll
  for (int i = 0; i < 32; ++i) acc2[i] = 0.f;
#pragma unroll 1
  for (int c = 0; c < 8; ++c) {
    float a[16];
#pragma unroll
    for (int i = 0; i < 16; ++i) a[i] = 0.f;
    const float* w1r = w1t + c * 128 + g * 16;
#pragma unroll 1
    for (int ci = 0; ci < 256; ++ci) {
      float r = U[lane][ci];
      const float* wr = w1r + ci * HID_;            // uniform -> s_load
#pragma unroll
      for (int k2 = 0; k2 < 16; ++k2) a[k2] = fmaf(wr[k2], r, a[k2]);
    }
    __syncthreads();                                 // previous chunk's Hb readers done
#pragma unroll
    for (int k2 = 0; k2 < 16; ++k2) {
      int h = c * 128 + g * 16 + k2;
      float vr = a[k2] + fc1b[h];
      float vb = vr * cb1[h] + cb1[HID_ + h];
      Hb[lane][g * 16 + k2] = 0.5f * vb * (1.f + erff(vb * 0.70710678118654752f));
    }
    __syncthreads();
    const float* w2r = w2t + (c * 128) * C_ + g * 32;
#pragma unroll 1
    for (int hh = 0; hh < 128; ++hh) {
      float hv = Hb[lane][hh];
      const float* wr = w2r + hh * C_;              // uniform -> s_load
#pragma unroll
      for (int k2 = 0; k2 < 32; ++k2) acc2[k2] = fmaf(wr[k2], hv, acc2[k2]);
    }
  }
  int s = s0 + lane;
#pragma unroll
  for (int k2 = 0; k2 < 32; ++k2) {
    int co = g * 32 + k2;
    int xi = (b * C_ + co) * THW + s;
    float h2 = (acc2[k2] + fc2b[co]) * cb2[co] + cb2[C_ + co];
    out[xi] = xp[xi] + h2;
  }
}

// ---------------- launch ----------------
extern "C" void kernel_launch(void* const* d_in, const int* in_sizes, int n_in,
                              void* d_out, int out_size, void* d_ws, size_t ws_size,
                              hipStream_t stream)
{
  const float* x    = (const float*)d_in[0];
  const float* n1g  = (const float*)d_in[1];
  const float* n1b  = (const float*)d_in[2];
  const float* n1m  = (const float*)d_in[3];
  const float* n1v  = (const float*)d_in[4];
  const float* qkvw = (const float*)d_in[5];
  const float* qbng = (const float*)d_in[6];
  const float* qbnb = (const float*)d_in[7];
  const float* qbnm = (const float*)d_in[8];
  const float* qbnv = (const float*)d_in[9];
  const float* projw= (const float*)d_in[10];
  const float* projb= (const float*)d_in[11];
  const float* n2g  = (const float*)d_in[12];
  const float* n2b  = (const float*)d_in[13];
  const float* n2m  = (const float*)d_in[14];
  const float* n2v  = (const float*)d_in[15];
  const float* fc1w = (const float*)d_in[16];
  const float* fc1b = (const float*)d_in[17];
  const float* b1g  = (const float*)d_in[18];
  const float* b1b  = (const float*)d_in[19];
  const float* b1m  = (const float*)d_in[20];
  const float* b1v  = (const float*)d_in[21];
  const float* fc2w = (const float*)d_in[22];
  const float* fc2b = (const float*)d_in[23];
  const float* b2g  = (const float*)d_in[24];
  const float* b2b  = (const float*)d_in[25];
  const float* b2m  = (const float*)d_in[26];
  const float* b2v  = (const float*)d_in[27];

  float* wsf     = (float*)d_ws;
  float* c_n1    = wsf;                         // 512
  float* c_qbn   = wsf + 512;                   // 1536
  float* c_n2    = wsf + 2048;                  // 512
  float* c_b1    = wsf + 2560;                  // 2048
  float* c_b2    = wsf + 4608;                  // 512
  float* wt_conv = wsf + 5120;                  // 2304*768
  float* projt   = wt_conv + KCONV * 768;       // 65536
  float* w1t     = projt + 256 * 256;           // 262144
  float* w2t     = w1t + 256 * 1024;            // 262144
  float* qw      = w2t + 1024 * 256;            // 4227072
  float* kw      = qw + 4227072;
  float* vw      = kw + 4227072;
  float* aw      = vw + 4227072;                // total 19,272,704 floats (~77MB)

  bn_pre<<<1, 256, 0, stream>>>(n1g, n1b, n1m, n1v, c_n1, 256);
  bn_pre<<<3, 256, 0, stream>>>(qbng, qbnb, qbnm, qbnv, c_qbn, 768);
  bn_pre<<<1, 256, 0, stream>>>(n2g, n2b, n2m, n2v, c_n2, 256);
  bn_pre<<<4, 256, 0, stream>>>(b1g, b1b, b1m, b1v, c_b1, 1024);
  bn_pre<<<1, 256, 0, stream>>>(b2g, b2b, b2m, b2v, c_b2, 256);
  tr_conv<<<6912, 256, 0, stream>>>(qkvw, wt_conv);
  tr_mat<<<256, 256, 0, stream>>>(projw, projt, 256, 256);
  tr_mat<<<1024, 256, 0, stream>>>(fc1w, w1t, 1024, 256);
  tr_mat<<<1024, 256, 0, stream>>>(fc2w, w2t, 256, 1024);

  dim3 gconv(258, 3);
  conv_qkv<<<gconv, 256, 0, stream>>>(x, wt_conv, c_n1, c_qbn, qw, kw, vw);
  attn_k<<<512, 256, 0, stream>>>(qw, kw, vw, aw);
  proj_resize<<<2176, 256, 0, stream>>>(aw, projt, projb, x, (float*)d_out);
  mlp_k<<<2176, 512, 0, stream>>>((const float*)d_out, w1t, fc1b, w2t, fc2b,
                                  c_n2, c_b1, c_b2, (float*)d_out);
}

// Round 2
// 3598.413 us; speedup vs baseline: 2.8586x; 2.8586x over previous
//
#include <hip/hip_runtime.h>
#include <math.h>

// ---------------- problem constants ----------------
#define B_   64
#define C_   256
#define T_   128
#define J_   17
#define THW  2176      // T_*J_
#define HC   43
#define WC   6
#define P_   258       // HC*WC
#define NH_  8
#define HD_  32
#define HID_ 1024
#define KCONV 2304     // 256*9

typedef __attribute__((ext_vector_type(8))) short bf16x8;
typedef __attribute__((ext_vector_type(4))) float f32x4;

__device__ __forceinline__ unsigned f2b1(float x) {
  union { float f; unsigned u; } c; c.f = x;
  return (c.u + 0x7fffu + ((c.u >> 16) & 1u)) >> 16;   // RNE bf16
}
__device__ __forceinline__ unsigned packbf(float a, float b) {
  return f2b1(a) | (f2b1(b) << 16);
}
__device__ __forceinline__ float gelu_f(float v) {
  return 0.5f * v * (1.f + erff(v * 0.70710678118654752f));
}

// ---------------- precompute kernels ----------------
__global__ void bn_pre(const float* __restrict__ g, const float* __restrict__ b,
                       const float* __restrict__ m, const float* __restrict__ v,
                       float* __restrict__ o, int n)
{
  for (int i = blockIdx.x * blockDim.x + threadIdx.x; i < n; i += gridDim.x * blockDim.x) {
    float inv = g[i] / sqrtf(v[i] + 1e-5f);
    o[i]     = inv;
    o[n + i] = b[i] - m[i] * inv;
  }
}

// folded BN with preceding conv bias: y = (a + bias)*inv + (b - m*inv)
__global__ void bn_pre_bias(const float* __restrict__ g, const float* __restrict__ b,
                            const float* __restrict__ m, const float* __restrict__ v,
                            const float* __restrict__ bias, float* __restrict__ o, int n)
{
  for (int i = blockIdx.x * blockDim.x + threadIdx.x; i < n; i += gridDim.x * blockDim.x) {
    float inv = g[i] / sqrtf(v[i] + 1e-5f);
    o[i]     = inv;
    o[n + i] = b[i] - m[i] * inv + bias[i] * inv;
  }
}

// qkv_w (768,256,3,3) flat = co*2304 + (ci*9+kh*3+kw)  ->  wt[k*768 + co]
__global__ void tr_conv(const float* __restrict__ w, float* __restrict__ wt)
{
  int i = blockIdx.x * 256 + threadIdx.x;
  if (i < 768 * KCONV) {
    int co = i / KCONV, k = i - co * KCONV;
    wt[k * 768 + co] = w[i];
  }
}

// w (R,C) row-major -> wt[c*R + r]
__global__ void tr_mat(const float* __restrict__ w, float* __restrict__ wt, int R, int C)
{
  int i = blockIdx.x * 256 + threadIdx.x;
  if (i < R * C) {
    int r = i / C, c = i - r * C;
    wt[c * R + r] = w[i];
  }
}

// weight (M,K) fp32 -> bf16 MFMA A-fragments:
// frag f = ((rt*(K/32) + kt)*64 + lane)*8 + j  holds  A[16*rt + (lane&15)][32*kt + 8*(lane>>4) + j]
__global__ void mk_frag(const float* __restrict__ w, unsigned short* __restrict__ wf,
                        int M, int K)
{
  int i = blockIdx.x * 256 + threadIdx.x;
  if (i >= M * K) return;
  int j = i & 7, l = (i >> 3) & 63;
  int rest = i >> 9;
  int nkt = K >> 5;
  int kt = rest % nkt, rt = rest / nkt;
  int row = 16 * rt + (l & 15);
  int k   = 32 * kt + 8 * (l >> 4) + j;
  wf[i] = (unsigned short)f2b1(w[row * K + k]);
}

// ---------------- conv qkv: implicit GEMM M=768 K=2304 N=16512 ----------------
__global__ __launch_bounds__(256) void conv_qkv(
    const float* __restrict__ x, const float* __restrict__ wt,
    const float* __restrict__ cn1, const float* __restrict__ cqbn,
    float* __restrict__ qo, float* __restrict__ ko, float* __restrict__ vo)
{
  __shared__ float gl[64][257];
  const int tid  = threadIdx.x;
  const int lane = tid & 63;
  const int g    = __builtin_amdgcn_readfirstlane(tid >> 6);
  const int col0 = blockIdx.x * 64;
  const int mb   = blockIdx.y;

  float acc[64];
#pragma unroll
  for (int i = 0; i < 64; ++i) acc[i] = 0.f;

  for (int ch = 0; ch < 9; ++ch) {
    __syncthreads();
    for (int e = tid; e < 64 * 256; e += 256) {
      int kk = e >> 6, col = e & 63;
      int gcol = col0 + col;
      int b = gcol / P_, p = gcol - b * P_;
      int oh = p / WC, ow = p - oh * WC;
      int k = ch * 256 + kk;
      int ci = k / 9; int rem = k - ci * 9;
      int kh = rem / 3, kw = rem - kh * 3;
      int ir = 3 * oh - 1 + kh;
      int ic = 3 * ow - 1 + kw;
      float val = 0.f;
      if ((unsigned)ir < (unsigned)T_ && (unsigned)ic < (unsigned)J_)
        val = x[((b * C_ + ci) * T_ + ir) * J_ + ic] * cn1[ci] + cn1[C_ + ci];
      gl[col][kk] = val;
    }
    __syncthreads();
#pragma unroll 1
    for (int kk = 0; kk < 256; ++kk) {
      float r = gl[lane][kk];
      const float* wr = wt + (ch * 256 + kk) * 768 + mb * 256 + g * 64;
#pragma unroll
      for (int k2 = 0; k2 < 64; ++k2) acc[k2] = fmaf(wr[k2], r, acc[k2]);
    }
  }

  int gcol = col0 + lane;
  int b = gcol / P_, p = gcol - b * P_;
#pragma unroll
  for (int k2 = 0; k2 < 64; ++k2) {
    int co = mb * 256 + g * 64 + k2;
    float vb = acc[k2] * cqbn[co] + cqbn[768 + co];
    float ge = gelu_f(vb);
    int which = co >> 8, rr = co & 255, head = rr >> 5, d = rr & 31;
    int idx = ((b * NH_ + head) * P_ + p) * HD_ + d;
    if (which == 0)      qo[idx] = ge * 0.176776695296636881f;
    else if (which == 1) ko[idx] = ge;
    else                 vo[idx] = ge;
  }
}

// ---------------- attention: one block per (b,h) ----------------
__global__ __launch_bounds__(256) void attn_k(
    const float* __restrict__ q, const float* __restrict__ k,
    const float* __restrict__ v, float* __restrict__ o)
{
  __shared__ float Kl[P_][33];
  __shared__ float Vl[P_][33];
  __shared__ float pb[4][264];
  const int bh = blockIdx.x;
  const int tid = threadIdx.x, lane = tid & 63, w = tid >> 6;
  const float* kb = k + bh * (P_ * HD_);
  const float* vb = v + bh * (P_ * HD_);
  for (int e = tid; e < P_ * HD_; e += 256) {
    Kl[e >> 5][e & 31] = kb[e];
    Vl[e >> 5][e & 31] = vb[e];
  }
  __syncthreads();
  for (int r = w; r < P_; r += 4) {
    const float4* qr = (const float4*)(q + (bh * P_ + r) * HD_);
    float qv[32];
#pragma unroll
    for (int i = 0; i < 8; ++i) {
      float4 t = qr[i];
      qv[4*i] = t.x; qv[4*i+1] = t.y; qv[4*i+2] = t.z; qv[4*i+3] = t.w;
    }
    float s[5];
    float m = -1e30f;
#pragma unroll
    for (int i = 0; i < 5; ++i) {
      int p = lane + (i << 6);
      float a = -1e30f;
      if (p < P_) {
        a = 0.f;
#pragma unroll
        for (int d = 0; d < 32; ++d) a = fmaf(qv[d], Kl[p][d], a);
      }
      s[i] = a;
      m = fmaxf(m, a);
    }
#pragma unroll
    for (int off = 32; off > 0; off >>= 1) m = fmaxf(m, __shfl_xor(m, off));
    float sum = 0.f;
#pragma unroll
    for (int i = 0; i < 5; ++i) {
      int p = lane + (i << 6);
      float e = (p < P_) ? expf(s[i] - m) : 0.f;
      s[i] = e;
      sum += e;
    }
#pragma unroll
    for (int off = 32; off > 0; off >>= 1) sum += __shfl_xor(sum, off);
    float rinv = 1.f / sum;
#pragma unroll
    for (int i = 0; i < 5; ++i) {
      int p = lane + (i << 6);
      if (p < P_) pb[w][p] = s[i] * rinv;
    }
    __builtin_amdgcn_wave_barrier();
    int half = lane >> 5, d = lane & 31;
    float a = 0.f;
    int p0 = half * 129;
#pragma unroll 1
    for (int p = p0; p < p0 + 129; ++p) a = fmaf(pb[w][p], Vl[p][d], a);
    a += __shfl_xor(a, 32);
    if (lane < 32) o[(bh * P_ + r) * HD_ + d] = a;
    __builtin_amdgcn_wave_barrier();
  }
}

// ---------------- bilinear resize + 1x1 proj + residual -> x' in d_out ----------------
__global__ __launch_bounds__(256) void proj_resize(
    const float* __restrict__ ao, const float* __restrict__ projt,
    const float* __restrict__ projb, const float* __restrict__ x,
    float* __restrict__ out)
{
  __shared__ float R[64][257];
  __shared__ float cw[64][4];
  __shared__ int   cix[64][4];
  const int tid = threadIdx.x, lane = tid & 63;
  const int g   = __builtin_amdgcn_readfirstlane(tid >> 6);
  const int blk = blockIdx.x;
  const int b   = blk / 34;
  const int s0  = (blk - b * 34) * 64;
  if (tid < 64) {
    int s = s0 + tid;
    int t = s / J_, j = s - t * J_;
    float ft = fmaxf((t + 0.5f) * ((float)HC / (float)T_) - 0.5f, 0.f);
    float fj = fmaxf((j + 0.5f) * ((float)WC / (float)J_) - 0.5f, 0.f);
    int i0 = (int)ft; if (i0 > HC - 1) i0 = HC - 1;
    int j0 = (int)fj; if (j0 > WC - 1) j0 = WC - 1;
    int i1 = min(i0 + 1, HC - 1);
    int j1 = min(j0 + 1, WC - 1);
    float wt_ = ft - (float)i0, wj_ = fj - (float)j0;
    cix[tid][0] = i0 * WC + j0; cix[tid][1] = i0 * WC + j1;
    cix[tid][2] = i1 * WC + j0; cix[tid][3] = i1 * WC + j1;
    cw[tid][0] = (1.f - wt_) * (1.f - wj_); cw[tid][1] = (1.f - wt_) * wj_;
    cw[tid][2] = wt_ * (1.f - wj_);         cw[tid][3] = wt_ * wj_;
  }
  __syncthreads();
  for (int e = tid; e < 64 * 256; e += 256) {
    int ci = e >> 6, col = e & 63;
    int head = ci >> 5, d = ci & 31;
    const float* A = ao + (b * NH_ + head) * (P_ * HD_) + d;
    R[col][ci] = cw[col][0] * A[cix[col][0] * HD_] + cw[col][1] * A[cix[col][1] * HD_]
               + cw[col][2] * A[cix[col][2] * HD_] + cw[col][3] * A[cix[col][3] * HD_];
  }
  __syncthreads();
  float acc[64];
#pragma unroll
  for (int i = 0; i < 64; ++i) acc[i] = 0.f;
#pragma unroll 1
  for (int ci = 0; ci < 256; ++ci) {
    float r = R[lane][ci];
    const float* wr = projt + ci * 256 + g * 64;
#pragma unroll
    for (int k2 = 0; k2 < 64; ++k2) acc[k2] = fmaf(wr[k2], r, acc[k2]);
  }
  int s = s0 + lane;
#pragma unroll
  for (int k2 = 0; k2 < 64; ++k2) {
    int co = g * 64 + k2;
    int xi = (b * C_ + co) * THW + s;
    out[xi] = x[xi] + projb[co] + acc[k2];
  }
}

// ---------------- fused MLP via bf16 MFMA ----------------
// block = 64 output columns, 4 waves; Y(256) = W2(256x1024) gelu(bn(W1(1024x256) U))
__global__ __launch_bounds__(256) void mlp_mfma(
    const float* __restrict__ xp,
    const unsigned short* __restrict__ w1f, const unsigned short* __restrict__ w2f,
    const float* __restrict__ cn2, const float* __restrict__ cb1,
    const float* __restrict__ cb2, float* __restrict__ out)
{
  __shared__ unsigned short U[64 * 264];    // [col][ci], stride 264 bf16 (16B-aligned rows)
  __shared__ unsigned short Hs[64 * 136];   // [col][h_local], stride 136 bf16
  const int tid = threadIdx.x;
  const int l   = tid & 63, w = tid >> 6;
  const int c   = l & 15, kg = l >> 4;      // B-frag col-in-tile / k-group
  const int blk = blockIdx.x;
  const int b   = blk / 34;
  const int s0  = (blk - b * 34) * 64;

  // ---- stage U = bf16(bn2(xp)) ----
  {
    const int col = tid & 63;
    const int ofs = tid >> 6;
#pragma unroll 1
    for (int cp = ofs; cp < 128; cp += 4) {
      int ci0 = 2 * cp;
      float sa = cn2[ci0],     oa = cn2[C_ + ci0];
      float sb = cn2[ci0 + 1], ob = cn2[C_ + ci0 + 1];
      float va = xp[(b * C_ + ci0) * THW + s0 + col] * sa + oa;
      float vb = xp[(b * C_ + ci0 + 1) * THW + s0 + col] * sb + ob;
      *(unsigned*)&U[col * 264 + ci0] = packbf(va, vb);
    }
  }
  __syncthreads();

  f32x4 acc2[4][4];
#pragma unroll
  for (int mf = 0; mf < 4; ++mf)
#pragma unroll
    for (int nf = 0; nf < 4; ++nf)
      acc2[mf][nf] = (f32x4){0.f, 0.f, 0.f, 0.f};

  for (int ch = 0; ch < 8; ++ch) {
    // ---- GEMM1: H_chunk(128) x cols(64), K=256; wave owns 32 hidden rows ----
    f32x4 acc1[2][4];
#pragma unroll
    for (int mf = 0; mf < 2; ++mf)
#pragma unroll
      for (int nf = 0; nf < 4; ++nf)
        acc1[mf][nf] = (f32x4){0.f, 0.f, 0.f, 0.f};

#pragma unroll
    for (int ks = 0; ks < 8; ++ks) {
      bf16x8 a0 = *(const bf16x8*)&w1f[(((ch * 8 + 2 * w + 0) * 8 + ks) * 64 + l) * 8];
      bf16x8 a1 = *(const bf16x8*)&w1f[(((ch * 8 + 2 * w + 1) * 8 + ks) * 64 + l) * 8];
      bf16x8 bf0 = *(const bf16x8*)&U[(0  + c) * 264 + 32 * ks + 8 * kg];
      bf16x8 bf1 = *(const bf16x8*)&U[(16 + c) * 264 + 32 * ks + 8 * kg];
      bf16x8 bf2 = *(const bf16x8*)&U[(32 + c) * 264 + 32 * ks + 8 * kg];
      bf16x8 bf3 = *(const bf16x8*)&U[(48 + c) * 264 + 32 * ks + 8 * kg];
      acc1[0][0] = __builtin_amdgcn_mfma_f32_16x16x32_bf16(a0, bf0, acc1[0][0], 0, 0, 0);
      acc1[0][1] = __builtin_amdgcn_mfma_f32_16x16x32_bf16(a0, bf1, acc1[0][1], 0, 0, 0);
      acc1[0][2] = __builtin_amdgcn_mfma_f32_16x16x32_bf16(a0, bf2, acc1[0][2], 0, 0, 0);
      acc1[0][3] = __builtin_amdgcn_mfma_f32_16x16x32_bf16(a0, bf3, acc1[0][3], 0, 0, 0);
      acc1[1][0] = __builtin_amdgcn_mfma_f32_16x16x32_bf16(a1, bf0, acc1[1][0], 0, 0, 0);
      acc1[1][1] = __builtin_amdgcn_mfma_f32_16x16x32_bf16(a1, bf1, acc1[1][1], 0, 0, 0);
      acc1[1][2] = __builtin_amdgcn_mfma_f32_16x16x32_bf16(a1, bf2, acc1[1][2], 0, 0, 0);
      acc1[1][3] = __builtin_amdgcn_mfma_f32_16x16x32_bf16(a1, bf3, acc1[1][3], 0, 0, 0);
    }

    __syncthreads();   // previous chunk's GEMM2 done reading Hs

    // ---- bn1 + gelu + pack to Hs ----
#pragma unroll
    for (int mf = 0; mf < 2; ++mf) {
      int hbase = ch * 128 + 32 * w + 16 * mf + 4 * kg;
      float sc0 = cb1[hbase + 0], sc1 = cb1[hbase + 1], sc2 = cb1[hbase + 2], sc3 = cb1[hbase + 3];
      float of0 = cb1[HID_ + hbase + 0], of1 = cb1[HID_ + hbase + 1];
      float of2 = cb1[HID_ + hbase + 2], of3 = cb1[HID_ + hbase + 3];
      int kloc = 32 * w + 16 * mf + 4 * kg;
#pragma unroll
      for (int nf = 0; nf < 4; ++nf) {
        float g0 = gelu_f(acc1[mf][nf][0] * sc0 + of0);
        float g1 = gelu_f(acc1[mf][nf][1] * sc1 + of1);
        float g2 = gelu_f(acc1[mf][nf][2] * sc2 + of2);
        float g3 = gelu_f(acc1[mf][nf][3] * sc3 + of3);
        int col = 16 * nf + c;
        *(unsigned*)&Hs[col * 136 + kloc]     = packbf(g0, g1);
        *(unsigned*)&Hs[col * 136 + kloc + 2] = packbf(g2, g3);
      }
    }
    __syncthreads();   // Hs ready

    // ---- GEMM2 accumulate: Y(256) += W2_chunk . H_chunk, K=128; wave owns 64 rows ----
#pragma unroll
    for (int ks = 0; ks < 4; ++ks) {
      bf16x8 a20 = *(const bf16x8*)&w2f[(((4 * w + 0) * 32 + ch * 4 + ks) * 64 + l) * 8];
      bf16x8 a21 = *(const bf16x8*)&w2f[(((4 * w + 1) * 32 + ch * 4 + ks) * 64 + l) * 8];
      bf16x8 a22 = *(const bf16x8*)&w2f[(((4 * w + 2) * 32 + ch * 4 + ks) * 64 + l) * 8];
      bf16x8 a23 = *(const bf16x8*)&w2f[(((4 * w + 3) * 32 + ch * 4 + ks) * 64 + l) * 8];
      bf16x8 h0 = *(const bf16x8*)&Hs[(0  + c) * 136 + 32 * ks + 8 * kg];
      bf16x8 h1 = *(const bf16x8*)&Hs[(16 + c) * 136 + 32 * ks + 8 * kg];
      bf16x8 h2 = *(const bf16x8*)&Hs[(32 + c) * 136 + 32 * ks + 8 * kg];
      bf16x8 h3 = *(const bf16x8*)&Hs[(48 + c) * 136 + 32 * ks + 8 * kg];
      acc2[0][0] = __builtin_amdgcn_mfma_f32_16x16x32_bf16(a20, h0, acc2[0][0], 0, 0, 0);
      acc2[0][1] = __builtin_amdgcn_mfma_f32_16x16x32_bf16(a20, h1, acc2[0][1], 0, 0, 0);
      acc2[0][2] = __builtin_amdgcn_mfma_f32_16x16x32_bf16(a20, h2, acc2[0][2], 0, 0, 0);
      acc2[0][3] = __builtin_amdgcn_mfma_f32_16x16x32_bf16(a20, h3, acc2[0][3], 0, 0, 0);
      acc2[1][0] = __builtin_amdgcn_mfma_f32_16x16x32_bf16(a21, h0, acc2[1][0], 0, 0, 0);
      acc2[1][1] = __builtin_amdgcn_mfma_f32_16x16x32_bf16(a21, h1, acc2[1][1], 0, 0, 0);
      acc2[1][2] = __builtin_amdgcn_mfma_f32_16x16x32_bf16(a21, h2, acc2[1][2], 0, 0, 0);
      acc2[1][3] = __builtin_amdgcn_mfma_f32_16x16x32_bf16(a21, h3, acc2[1][3], 0, 0, 0);
      acc2[2][0] = __builtin_amdgcn_mfma_f32_16x16x32_bf16(a22, h0, acc2[2][0], 0, 0, 0);
      acc2[2][1] = __builtin_amdgcn_mfma_f32_16x16x32_bf16(a22, h1, acc2[2][1], 0, 0, 0);
      acc2[2][2] = __builtin_amdgcn_mfma_f32_16x16x32_bf16(a22, h2, acc2[2][2], 0, 0, 0);
      acc2[2][3] = __builtin_amdgcn_mfma_f32_16x16x32_bf16(a22, h3, acc2[2][3], 0, 0, 0);
      acc2[3][0] = __builtin_amdgcn_mfma_f32_16x16x32_bf16(a23, h0, acc2[3][0], 0, 0, 0);
      acc2[3][1] = __builtin_amdgcn_mfma_f32_16x16x32_bf16(a23, h1, acc2[3][1], 0, 0, 0);
      acc2[3][2] = __builtin_amdgcn_mfma_f32_16x16x32_bf16(a23, h2, acc2[3][2], 0, 0, 0);
      acc2[3][3] = __builtin_amdgcn_mfma_f32_16x16x32_bf16(a23, h3, acc2[3][3], 0, 0, 0);
    }
  }

  // ---- epilogue: bn2-out (+fc2 bias folded) + residual ----
#pragma unroll
  for (int mf = 0; mf < 4; ++mf) {
    int cob = 64 * w + 16 * mf + 4 * kg;
    float sc0 = cb2[cob + 0], sc1 = cb2[cob + 1], sc2 = cb2[cob + 2], sc3 = cb2[cob + 3];
    float of0 = cb2[C_ + cob + 0], of1 = cb2[C_ + cob + 1];
    float of2 = cb2[C_ + cob + 2], of3 = cb2[C_ + cob + 3];
#pragma unroll
    for (int nf = 0; nf < 4; ++nf) {
      int s = s0 + 16 * nf + c;
      int xi0 = (b * C_ + cob) * THW + s;
      out[xi0]            = xp[xi0]            + acc2[mf][nf][0] * sc0 + of0;
      out[xi0 + THW]      = xp[xi0 + THW]      + acc2[mf][nf][1] * sc1 + of1;
      out[xi0 + 2 * THW]  = xp[xi0 + 2 * THW]  + acc2[mf][nf][2] * sc2 + of2;
      out[xi0 + 3 * THW]  = xp[xi0 + 3 * THW]  + acc2[mf][nf][3] * sc3 + of3;
    }
  }
}

// ---------------- launch ----------------
extern "C" void kernel_launch(void* const* d_in, const int* in_sizes, int n_in,
                              void* d_out, int out_size, void* d_ws, size_t ws_size,
                              hipStream_t stream)
{
  const float* x    = (const float*)d_in[0];
  const float* n1g  = (const float*)d_in[1];
  const float* n1b  = (const float*)d_in[2];
  const float* n1m  = (const float*)d_in[3];
  const float* n1v  = (const float*)d_in[4];
  const float* qkvw = (const float*)d_in[5];
  const float* qbng = (const float*)d_in[6];
  const float* qbnb = (const float*)d_in[7];
  const float* qbnm = (const float*)d_in[8];
  const float* qbnv = (const float*)d_in[9];
  const float* projw= (const float*)d_in[10];
  const float* projb= (const float*)d_in[11];
  const float* n2g  = (const float*)d_in[12];
  const float* n2b  = (const float*)d_in[13];
  const float* n2m  = (const float*)d_in[14];
  const float* n2v  = (const float*)d_in[15];
  const float* fc1w = (const float*)d_in[16];
  const float* fc1b = (const float*)d_in[17];
  const float* b1g  = (const float*)d_in[18];
  const float* b1b  = (const float*)d_in[19];
  const float* b1m  = (const float*)d_in[20];
  const float* b1v  = (const float*)d_in[21];
  const float* fc2w = (const float*)d_in[22];
  const float* fc2b = (const float*)d_in[23];
  const float* b2g  = (const float*)d_in[24];
  const float* b2b  = (const float*)d_in[25];
  const float* b2m  = (const float*)d_in[26];
  const float* b2v  = (const float*)d_in[27];

  float* wsf     = (float*)d_ws;
  float* c_n1    = wsf;                         // 512
  float* c_qbn   = wsf + 512;                   // 1536
  float* c_n2    = wsf + 2048;                  // 512
  float* c_b1    = wsf + 2560;                  // 2048 (fc1 bias folded)
  float* c_b2    = wsf + 4608;                  // 512  (fc2 bias folded)
  float* wt_conv = wsf + 5120;                  // 2304*768 = 1769472
  float* projt   = wt_conv + KCONV * 768;       // 65536
  unsigned short* w1f = (unsigned short*)(projt + 65536);       // 262144 bf16 = 131072 f
  unsigned short* w2f = (unsigned short*)(projt + 65536 + 131072); // 262144 bf16
  float* qw      = projt + 65536 + 262144;      // 4227072
  float* kw      = qw + 4227072;
  float* vw      = kw + 4227072;
  float* aw      = vw + 4227072;                // total ~76.0 MB

  bn_pre<<<1, 256, 0, stream>>>(n1g, n1b, n1m, n1v, c_n1, 256);
  bn_pre<<<3, 256, 0, stream>>>(qbng, qbnb, qbnm, qbnv, c_qbn, 768);
  bn_pre<<<1, 256, 0, stream>>>(n2g, n2b, n2m, n2v, c_n2, 256);
  bn_pre_bias<<<4, 256, 0, stream>>>(b1g, b1b, b1m, b1v, fc1b, c_b1, 1024);
  bn_pre_bias<<<1, 256, 0, stream>>>(b2g, b2b, b2m, b2v, fc2b, c_b2, 256);
  tr_conv<<<6912, 256, 0, stream>>>(qkvw, wt_conv);
  tr_mat<<<256, 256, 0, stream>>>(projw, projt, 256, 256);
  mk_frag<<<1024, 256, 0, stream>>>(fc1w, w1f, 1024, 256);
  mk_frag<<<1024, 256, 0, stream>>>(fc2w, w2f, 256, 1024);

  dim3 gconv(258, 3);
  conv_qkv<<<gconv, 256, 0, stream>>>(x, wt_conv, c_n1, c_qbn, qw, kw, vw);
  attn_k<<<512, 256, 0, stream>>>(qw, kw, vw, aw);
  proj_resize<<<2176, 256, 0, stream>>>(aw, projt, projb, x, (float*)d_out);
  mlp_mfma<<<2176, 256, 0, stream>>>((const float*)d_out, w1f, w2f,
                                     c_n2, c_b1, c_b2, (float*)d_out);
}

// Round 3
// 1497.640 us; speedup vs baseline: 6.8684x; 2.4027x over previous
//
#include <hip/hip_runtime.h>
#include <math.h>

// ---------------- problem constants ----------------
#define B_   64
#define C_   256
#define T_   128
#define J_   17
#define THW  2176      // T_*J_
#define HC   43
#define WC   6
#define P_   258       // HC*WC
#define NH_  8
#define HD_  32
#define HID_ 1024
#define KCONV 2304     // 256*9
#define NKT_CONV 72    // 2304/32

typedef __attribute__((ext_vector_type(8))) short bf16x8;
typedef __attribute__((ext_vector_type(4))) float f32x4;

__device__ __forceinline__ unsigned f2b1(float x) {
  union { float f; unsigned u; } c; c.f = x;
  return (c.u + 0x7fffu + ((c.u >> 16) & 1u)) >> 16;   // RNE bf16
}
__device__ __forceinline__ unsigned packbf(float a, float b) {
  return f2b1(a) | (f2b1(b) << 16);
}
__device__ __forceinline__ float gelu_f(float v) {
  return 0.5f * v * (1.f + erff(v * 0.70710678118654752f));
}

// ---------------- precompute kernels ----------------
__global__ void bn_pre(const float* __restrict__ g, const float* __restrict__ b,
                       const float* __restrict__ m, const float* __restrict__ v,
                       float* __restrict__ o, int n)
{
  for (int i = blockIdx.x * blockDim.x + threadIdx.x; i < n; i += gridDim.x * blockDim.x) {
    float inv = g[i] / sqrtf(v[i] + 1e-5f);
    o[i]     = inv;
    o[n + i] = b[i] - m[i] * inv;
  }
}

__global__ void bn_pre_bias(const float* __restrict__ g, const float* __restrict__ b,
                            const float* __restrict__ m, const float* __restrict__ v,
                            const float* __restrict__ bias, float* __restrict__ o, int n)
{
  for (int i = blockIdx.x * blockDim.x + threadIdx.x; i < n; i += gridDim.x * blockDim.x) {
    float inv = g[i] / sqrtf(v[i] + 1e-5f);
    o[i]     = inv;
    o[n + i] = b[i] - m[i] * inv + bias[i] * inv;
  }
}

// weight (M,K) fp32 row-major -> bf16 MFMA A-fragments
// frag i = ((rt*(K/32) + kt)*64 + l)*8 + j  holds  A[16*rt + (l&15)][32*kt + 8*(l>>4) + j]
__global__ void mk_frag(const float* __restrict__ w, unsigned short* __restrict__ wf,
                        int M, int K)
{
  int i = blockIdx.x * 256 + threadIdx.x;
  if (i >= M * K) return;
  int j = i & 7, l = (i >> 3) & 63;
  int rest = i >> 9;
  int nkt = K >> 5;
  int kt = rest % nkt, rt = rest / nkt;
  int row = 16 * rt + (l & 15);
  int k   = 32 * kt + 8 * (l >> 4) + j;
  wf[i] = (unsigned short)f2b1(w[row * K + k]);
}

// qkv conv weights (768,256,3,3) -> fragments with K reordered kernel-pos-major:
// k = kp*256 + ci  (kp = kh*3+kw)
__global__ void mk_frag_conv(const float* __restrict__ w, unsigned short* __restrict__ wf)
{
  int i = blockIdx.x * 256 + threadIdx.x;
  if (i >= 768 * KCONV) return;
  int j = i & 7, l = (i >> 3) & 63;
  int rest = i >> 9;
  int kt = rest % NKT_CONV, rt = rest / NKT_CONV;
  int row = 16 * rt + (l & 15);
  int k   = 32 * kt + 8 * (l >> 4) + j;
  int kp = k >> 8, ci = k & 255;
  wf[i] = (unsigned short)f2b1(w[row * KCONV + ci * 9 + kp]);
}

// ---------------- x-hat: bf16(bn1(x)) in NHWC  (written into d_out's dead space) ----
__global__ __launch_bounds__(256) void xhat_k(
    const float* __restrict__ x, const float* __restrict__ cn1,
    unsigned short* __restrict__ xt)
{
  __shared__ unsigned short Ux[64 * 264];
  const int blk = blockIdx.x;
  const int b = blk / 34;
  const int s0 = (blk - b * 34) * 64;
  const int tid = threadIdx.x;
  const int col = tid & 63, ofs = tid >> 6;
#pragma unroll 1
  for (int cp = ofs; cp < 128; cp += 4) {
    int ci0 = 2 * cp;
    float va = x[(b * C_ + ci0)     * THW + s0 + col] * cn1[ci0]     + cn1[C_ + ci0];
    float vb = x[(b * C_ + ci0 + 1) * THW + s0 + col] * cn1[ci0 + 1] + cn1[C_ + ci0 + 1];
    *(unsigned*)&Ux[col * 264 + ci0] = packbf(va, vb);
  }
  __syncthreads();
  const uint4* srcl = (const uint4*)&Ux[col * 264];
  uint4* dst = (uint4*)&xt[(size_t)(b * THW + s0 + col) * 256];
#pragma unroll
  for (int i = 0; i < 8; ++i) {
    int vi = ofs + 4 * i;
    dst[vi] = srcl[vi];
  }
}

// ---------------- conv qkv via MFMA: M=768 K=2304 N=16512 ----------------
// grid (258, 3); block 256 = 4 waves x 64 rows; 64 cols per block
__global__ __launch_bounds__(256) void conv_mfma(
    const unsigned short* __restrict__ xt, const unsigned short* __restrict__ wcf,
    const float* __restrict__ cqbn,
    float* __restrict__ qo, float* __restrict__ ko, float* __restrict__ vo)
{
  __shared__ unsigned short U[64 * 264];
  const int tid = threadIdx.x;
  const int l = tid & 63, w = tid >> 6;
  const int c = l & 15, kg = l >> 4;
  const int col0 = blockIdx.x * 64;
  const int mb = blockIdx.y;

  // staging geometry (col = l, quarter = w)
  const int gcol = col0 + l;
  const int b = gcol / P_, p = gcol - b * P_;
  const int oh = p / WC, ow = p - oh * WC;
  const unsigned short* xb = xt + (size_t)b * THW * 256;

  f32x4 acc[4][4];
#pragma unroll
  for (int mf = 0; mf < 4; ++mf)
#pragma unroll
    for (int nf = 0; nf < 4; ++nf)
      acc[mf][nf] = (f32x4){0.f, 0.f, 0.f, 0.f};

  for (int kp = 0; kp < 9; ++kp) {
    const int kh = kp / 3, kwp = kp - 3 * kh;
    const int ir = 3 * oh - 1 + kh, ic = 3 * ow - 1 + kwp;
    const bool valid = ((unsigned)ir < (unsigned)T_) && ((unsigned)ic < (unsigned)J_);
    __syncthreads();
    if (valid) {
      const uint4* src = (const uint4*)(xb + (size_t)(ir * J_ + ic) * 256);
#pragma unroll
      for (int i = 0; i < 8; ++i) {
        int vi = w + 4 * i;
        *(uint4*)&U[l * 264 + vi * 8] = src[vi];
      }
    } else {
      uint4 z = {0u, 0u, 0u, 0u};
#pragma unroll
      for (int i = 0; i < 8; ++i) {
        int vi = w + 4 * i;
        *(uint4*)&U[l * 264 + vi * 8] = z;
      }
    }
    __syncthreads();
#pragma unroll
    for (int ks = 0; ks < 8; ++ks) {
      const int kt = kp * 8 + ks;
      bf16x8 a0 = *(const bf16x8*)&wcf[(((mb * 16 + w * 4 + 0) * NKT_CONV + kt) * 64 + l) * 8];
      bf16x8 a1 = *(const bf16x8*)&wcf[(((mb * 16 + w * 4 + 1) * NKT_CONV + kt) * 64 + l) * 8];
      bf16x8 a2 = *(const bf16x8*)&wcf[(((mb * 16 + w * 4 + 2) * NKT_CONV + kt) * 64 + l) * 8];
      bf16x8 a3 = *(const bf16x8*)&wcf[(((mb * 16 + w * 4 + 3) * NKT_CONV + kt) * 64 + l) * 8];
      bf16x8 b0 = *(const bf16x8*)&U[(0  + c) * 264 + 32 * ks + 8 * kg];
      bf16x8 b1 = *(const bf16x8*)&U[(16 + c) * 264 + 32 * ks + 8 * kg];
      bf16x8 b2 = *(const bf16x8*)&U[(32 + c) * 264 + 32 * ks + 8 * kg];
      bf16x8 b3 = *(const bf16x8*)&U[(48 + c) * 264 + 32 * ks + 8 * kg];
      acc[0][0] = __builtin_amdgcn_mfma_f32_16x16x32_bf16(a0, b0, acc[0][0], 0, 0, 0);
      acc[0][1] = __builtin_amdgcn_mfma_f32_16x16x32_bf16(a0, b1, acc[0][1], 0, 0, 0);
      acc[0][2] = __builtin_amdgcn_mfma_f32_16x16x32_bf16(a0, b2, acc[0][2], 0, 0, 0);
      acc[0][3] = __builtin_amdgcn_mfma_f32_16x16x32_bf16(a0, b3, acc[0][3], 0, 0, 0);
      acc[1][0] = __builtin_amdgcn_mfma_f32_16x16x32_bf16(a1, b0, acc[1][0], 0, 0, 0);
      acc[1][1] = __builtin_amdgcn_mfma_f32_16x16x32_bf16(a1, b1, acc[1][1], 0, 0, 0);
      acc[1][2] = __builtin_amdgcn_mfma_f32_16x16x32_bf16(a1, b2, acc[1][2], 0, 0, 0);
      acc[1][3] = __builtin_amdgcn_mfma_f32_16x16x32_bf16(a1, b3, acc[1][3], 0, 0, 0);
      acc[2][0] = __builtin_amdgcn_mfma_f32_16x16x32_bf16(a2, b0, acc[2][0], 0, 0, 0);
      acc[2][1] = __builtin_amdgcn_mfma_f32_16x16x32_bf16(a2, b1, acc[2][1], 0, 0, 0);
      acc[2][2] = __builtin_amdgcn_mfma_f32_16x16x32_bf16(a2, b2, acc[2][2], 0, 0, 0);
      acc[2][3] = __builtin_amdgcn_mfma_f32_16x16x32_bf16(a2, b3, acc[2][3], 0, 0, 0);
      acc[3][0] = __builtin_amdgcn_mfma_f32_16x16x32_bf16(a3, b0, acc[3][0], 0, 0, 0);
      acc[3][1] = __builtin_amdgcn_mfma_f32_16x16x32_bf16(a3, b1, acc[3][1], 0, 0, 0);
      acc[3][2] = __builtin_amdgcn_mfma_f32_16x16x32_bf16(a3, b2, acc[3][2], 0, 0, 0);
      acc[3][3] = __builtin_amdgcn_mfma_f32_16x16x32_bf16(a3, b3, acc[3][3], 0, 0, 0);
    }
  }

  // epilogue: qbn + gelu + scatter to q/k/v (which = mb, uniform)
#pragma unroll
  for (int nf = 0; nf < 4; ++nf) {
    int gcol2 = col0 + 16 * nf + c;
    int b2 = gcol2 / P_, p2 = gcol2 - b2 * P_;
#pragma unroll
    for (int mf = 0; mf < 4; ++mf) {
      int col = w * 64 + 16 * mf + 4 * kg;      // row within 256 (channel)
#pragma unroll
      for (int jj = 0; jj < 4; ++jj) {
        int rr = col + jj;
        int co = mb * 256 + rr;
        float vv = acc[mf][nf][jj] * cqbn[co] + cqbn[768 + co];
        float ge = gelu_f(vv);
        int head = rr >> 5, d = rr & 31;
        int idx = ((b2 * NH_ + head) * P_ + p2) * HD_ + d;
        if (mb == 0)      qo[idx] = ge * 0.176776695296636881f;
        else if (mb == 1) ko[idx] = ge;
        else              vo[idx] = ge;
      }
    }
  }
}

// ---------------- attention: one block per (b,h) ----------------
__global__ __launch_bounds__(256) void attn_k(
    const float* __restrict__ q, const float* __restrict__ k,
    const float* __restrict__ v, float* __restrict__ o)
{
  __shared__ float Kl[P_][33];
  __shared__ float Vl[P_][33];
  __shared__ float pb[4][264];
  const int bh = blockIdx.x;
  const int tid = threadIdx.x, lane = tid & 63, w = tid >> 6;
  const float* kb = k + bh * (P_ * HD_);
  const float* vb = v + bh * (P_ * HD_);
  for (int e = tid; e < P_ * HD_; e += 256) {
    Kl[e >> 5][e & 31] = kb[e];
    Vl[e >> 5][e & 31] = vb[e];
  }
  __syncthreads();
  for (int r = w; r < P_; r += 4) {
    const float4* qr = (const float4*)(q + (bh * P_ + r) * HD_);
    float qv[32];
#pragma unroll
    for (int i = 0; i < 8; ++i) {
      float4 t = qr[i];
      qv[4*i] = t.x; qv[4*i+1] = t.y; qv[4*i+2] = t.z; qv[4*i+3] = t.w;
    }
    float s[5];
    float m = -1e30f;
#pragma unroll
    for (int i = 0; i < 5; ++i) {
      int p = lane + (i << 6);
      float a = -1e30f;
      if (p < P_) {
        a = 0.f;
#pragma unroll
        for (int d = 0; d < 32; ++d) a = fmaf(qv[d], Kl[p][d], a);
      }
      s[i] = a;
      m = fmaxf(m, a);
    }
#pragma unroll
    for (int off = 32; off > 0; off >>= 1) m = fmaxf(m, __shfl_xor(m, off));
    float sum = 0.f;
#pragma unroll
    for (int i = 0; i < 5; ++i) {
      int p = lane + (i << 6);
      float e = (p < P_) ? expf(s[i] - m) : 0.f;
      s[i] = e;
      sum += e;
    }
#pragma unroll
    for (int off = 32; off > 0; off >>= 1) sum += __shfl_xor(sum, off);
    float rinv = 1.f / sum;
#pragma unroll
    for (int i = 0; i < 5; ++i) {
      int p = lane + (i << 6);
      if (p < P_) pb[w][p] = s[i] * rinv;
    }
    __builtin_amdgcn_wave_barrier();
    int half = lane >> 5, d = lane & 31;
    float a = 0.f;
    int p0 = half * 129;
#pragma unroll 1
    for (int p = p0; p < p0 + 129; ++p) a = fmaf(pb[w][p], Vl[p][d], a);
    a += __shfl_xor(a, 32);
    if (lane < 32) o[(bh * P_ + r) * HD_ + d] = a;
    __builtin_amdgcn_wave_barrier();
  }
}

// ---------------- bilinear resize + 1x1 proj (MFMA) + residual -> x' in d_out ------
__global__ __launch_bounds__(256) void proj_mfma(
    const float* __restrict__ ao, const unsigned short* __restrict__ pwf,
    const float* __restrict__ projb, const float* __restrict__ x,
    float* __restrict__ out)
{
  __shared__ unsigned short R[64 * 264];
  __shared__ float cwS[64][4];
  __shared__ int   cixS[64][4];
  const int tid = threadIdx.x;
  const int l = tid & 63, w = tid >> 6;
  const int c = l & 15, kg = l >> 4;
  const int blk = blockIdx.x;
  const int b = blk / 34;
  const int s0 = (blk - b * 34) * 64;

  if (tid < 64) {
    int s = s0 + tid;
    int t = s / J_, j = s - t * J_;
    float ft = fmaxf((t + 0.5f) * ((float)HC / (float)T_) - 0.5f, 0.f);
    float fj = fmaxf((j + 0.5f) * ((float)WC / (float)J_) - 0.5f, 0.f);
    int i0 = (int)ft; if (i0 > HC - 1) i0 = HC - 1;
    int j0 = (int)fj; if (j0 > WC - 1) j0 = WC - 1;
    int i1 = min(i0 + 1, HC - 1);
    int j1 = min(j0 + 1, WC - 1);
    float wt_ = ft - (float)i0, wj_ = fj - (float)j0;
    cixS[tid][0] = i0 * WC + j0; cixS[tid][1] = i0 * WC + j1;
    cixS[tid][2] = i1 * WC + j0; cixS[tid][3] = i1 * WC + j1;
    cwS[tid][0] = (1.f - wt_) * (1.f - wj_); cwS[tid][1] = (1.f - wt_) * wj_;
    cwS[tid][2] = wt_ * (1.f - wj_);         cwS[tid][3] = wt_ * wj_;
  }
  __syncthreads();

  for (int e = tid; e < 64 * 128; e += 256) {
    int cp = e >> 6, col = e & 63;
    int ci0 = 2 * cp;
    int head = ci0 >> 5, d = ci0 & 31;
    const float* A = ao + (size_t)(b * NH_ + head) * (P_ * HD_) + d;
    float w0 = cwS[col][0], w1 = cwS[col][1], w2 = cwS[col][2], w3 = cwS[col][3];
    int i0 = cixS[col][0] * HD_, i1 = cixS[col][1] * HD_;
    int i2 = cixS[col][2] * HD_, i3 = cixS[col][3] * HD_;
    float v0 = w0 * A[i0]     + w1 * A[i1]     + w2 * A[i2]     + w3 * A[i3];
    float v1 = w0 * A[i0 + 1] + w1 * A[i1 + 1] + w2 * A[i2 + 1] + w3 * A[i3 + 1];
    *(unsigned*)&R[col * 264 + ci0] = packbf(v0, v1);
  }
  __syncthreads();

  f32x4 acc[4][4];
#pragma unroll
  for (int mf = 0; mf < 4; ++mf)
#pragma unroll
    for (int nf = 0; nf < 4; ++nf)
      acc[mf][nf] = (f32x4){0.f, 0.f, 0.f, 0.f};

#pragma unroll
  for (int ks = 0; ks < 8; ++ks) {
    bf16x8 a0 = *(const bf16x8*)&pwf[(((w * 4 + 0) * 8 + ks) * 64 + l) * 8];
    bf16x8 a1 = *(const bf16x8*)&pwf[(((w * 4 + 1) * 8 + ks) * 64 + l) * 8];
    bf16x8 a2 = *(const bf16x8*)&pwf[(((w * 4 + 2) * 8 + ks) * 64 + l) * 8];
    bf16x8 a3 = *(const bf16x8*)&pwf[(((w * 4 + 3) * 8 + ks) * 64 + l) * 8];
    bf16x8 b0 = *(const bf16x8*)&R[(0  + c) * 264 + 32 * ks + 8 * kg];
    bf16x8 b1 = *(const bf16x8*)&R[(16 + c) * 264 + 32 * ks + 8 * kg];
    bf16x8 b2 = *(const bf16x8*)&R[(32 + c) * 264 + 32 * ks + 8 * kg];
    bf16x8 b3 = *(const bf16x8*)&R[(48 + c) * 264 + 32 * ks + 8 * kg];
    acc[0][0] = __builtin_amdgcn_mfma_f32_16x16x32_bf16(a0, b0, acc[0][0], 0, 0, 0);
    acc[0][1] = __builtin_amdgcn_mfma_f32_16x16x32_bf16(a0, b1, acc[0][1], 0, 0, 0);
    acc[0][2] = __builtin_amdgcn_mfma_f32_16x16x32_bf16(a0, b2, acc[0][2], 0, 0, 0);
    acc[0][3] = __builtin_amdgcn_mfma_f32_16x16x32_bf16(a0, b3, acc[0][3], 0, 0, 0);
    acc[1][0] = __builtin_amdgcn_mfma_f32_16x16x32_bf16(a1, b0, acc[1][0], 0, 0, 0);
    acc[1][1] = __builtin_amdgcn_mfma_f32_16x16x32_bf16(a1, b1, acc[1][1], 0, 0, 0);
    acc[1][2] = __builtin_amdgcn_mfma_f32_16x16x32_bf16(a1, b2, acc[1][2], 0, 0, 0);
    acc[1][3] = __builtin_amdgcn_mfma_f32_16x16x32_bf16(a1, b3, acc[1][3], 0, 0, 0);
    acc[2][0] = __builtin_amdgcn_mfma_f32_16x16x32_bf16(a2, b0, acc[2][0], 0, 0, 0);
    acc[2][1] = __builtin_amdgcn_mfma_f32_16x16x32_bf16(a2, b1, acc[2][1], 0, 0, 0);
    acc[2][2] = __builtin_amdgcn_mfma_f32_16x16x32_bf16(a2, b2, acc[2][2], 0, 0, 0);
    acc[2][3] = __builtin_amdgcn_mfma_f32_16x16x32_bf16(a2, b3, acc[2][3], 0, 0, 0);
    acc[3][0] = __builtin_amdgcn_mfma_f32_16x16x32_bf16(a3, b0, acc[3][0], 0, 0, 0);
    acc[3][1] = __builtin_amdgcn_mfma_f32_16x16x32_bf16(a3, b1, acc[3][1], 0, 0, 0);
    acc[3][2] = __builtin_amdgcn_mfma_f32_16x16x32_bf16(a3, b2, acc[3][2], 0, 0, 0);
    acc[3][3] = __builtin_amdgcn_mfma_f32_16x16x32_bf16(a3, b3, acc[3][3], 0, 0, 0);
  }

#pragma unroll
  for (int mf = 0; mf < 4; ++mf) {
    int cob = w * 64 + 16 * mf + 4 * kg;
#pragma unroll
    for (int nf = 0; nf < 4; ++nf) {
      int s = s0 + 16 * nf + c;
#pragma unroll
      for (int jj = 0; jj < 4; ++jj) {
        int co = cob + jj;
        int xi = (b * C_ + co) * THW + s;
        out[xi] = x[xi] + projb[co] + acc[mf][nf][jj];
      }
    }
  }
}

// ---------------- fused MLP via bf16 MFMA (unchanged from round 2) ----------------
__global__ __launch_bounds__(256) void mlp_mfma(
    const float* __restrict__ xp,
    const unsigned short* __restrict__ w1f, const unsigned short* __restrict__ w2f,
    const float* __restrict__ cn2, const float* __restrict__ cb1,
    const float* __restrict__ cb2, float* __restrict__ out)
{
  __shared__ unsigned short U[64 * 264];
  __shared__ unsigned short Hs[64 * 136];
  const int tid = threadIdx.x;
  const int l   = tid & 63, w = tid >> 6;
  const int c   = l & 15, kg = l >> 4;
  const int blk = blockIdx.x;
  const int b   = blk / 34;
  const int s0  = (blk - b * 34) * 64;

  {
    const int col = tid & 63;
    const int ofs = tid >> 6;
#pragma unroll 1
    for (int cp = ofs; cp < 128; cp += 4) {
      int ci0 = 2 * cp;
      float sa = cn2[ci0],     oa = cn2[C_ + ci0];
      float sb = cn2[ci0 + 1], ob = cn2[C_ + ci0 + 1];
      float va = xp[(b * C_ + ci0) * THW + s0 + col] * sa + oa;
      float vb = xp[(b * C_ + ci0 + 1) * THW + s0 + col] * sb + ob;
      *(unsigned*)&U[col * 264 + ci0] = packbf(va, vb);
    }
  }
  __syncthreads();

  f32x4 acc2[4][4];
#pragma unroll
  for (int mf = 0; mf < 4; ++mf)
#pragma unroll
    for (int nf = 0; nf < 4; ++nf)
      acc2[mf][nf] = (f32x4){0.f, 0.f, 0.f, 0.f};

  for (int ch = 0; ch < 8; ++ch) {
    f32x4 acc1[2][4];
#pragma unroll
    for (int mf = 0; mf < 2; ++mf)
#pragma unroll
      for (int nf = 0; nf < 4; ++nf)
        acc1[mf][nf] = (f32x4){0.f, 0.f, 0.f, 0.f};

#pragma unroll
    for (int ks = 0; ks < 8; ++ks) {
      bf16x8 a0 = *(const bf16x8*)&w1f[(((ch * 8 + 2 * w + 0) * 8 + ks) * 64 + l) * 8];
      bf16x8 a1 = *(const bf16x8*)&w1f[(((ch * 8 + 2 * w + 1) * 8 + ks) * 64 + l) * 8];
      bf16x8 bf0 = *(const bf16x8*)&U[(0  + c) * 264 + 32 * ks + 8 * kg];
      bf16x8 bf1 = *(const bf16x8*)&U[(16 + c) * 264 + 32 * ks + 8 * kg];
      bf16x8 bf2 = *(const bf16x8*)&U[(32 + c) * 264 + 32 * ks + 8 * kg];
      bf16x8 bf3 = *(const bf16x8*)&U[(48 + c) * 264 + 32 * ks + 8 * kg];
      acc1[0][0] = __builtin_amdgcn_mfma_f32_16x16x32_bf16(a0, bf0, acc1[0][0], 0, 0, 0);
      acc1[0][1] = __builtin_amdgcn_mfma_f32_16x16x32_bf16(a0, bf1, acc1[0][1], 0, 0, 0);
      acc1[0][2] = __builtin_amdgcn_mfma_f32_16x16x32_bf16(a0, bf2, acc1[0][2], 0, 0, 0);
      acc1[0][3] = __builtin_amdgcn_mfma_f32_16x16x32_bf16(a0, bf3, acc1[0][3], 0, 0, 0);
      acc1[1][0] = __builtin_amdgcn_mfma_f32_16x16x32_bf16(a1, bf0, acc1[1][0], 0, 0, 0);
      acc1[1][1] = __builtin_amdgcn_mfma_f32_16x16x32_bf16(a1, bf1, acc1[1][1], 0, 0, 0);
      acc1[1][2] = __builtin_amdgcn_mfma_f32_16x16x32_bf16(a1, bf2, acc1[1][2], 0, 0, 0);
      acc1[1][3] = __builtin_amdgcn_mfma_f32_16x16x32_bf16(a1, bf3, acc1[1][3], 0, 0, 0);
    }

    __syncthreads();

#pragma unroll
    for (int mf = 0; mf < 2; ++mf) {
      int hbase = ch * 128 + 32 * w + 16 * mf + 4 * kg;
      float sc0 = cb1[hbase + 0], sc1 = cb1[hbase + 1], sc2 = cb1[hbase + 2], sc3 = cb1[hbase + 3];
      float of0 = cb1[HID_ + hbase + 0], of1 = cb1[HID_ + hbase + 1];
      float of2 = cb1[HID_ + hbase + 2], of3 = cb1[HID_ + hbase + 3];
      int kloc = 32 * w + 16 * mf + 4 * kg;
#pragma unroll
      for (int nf = 0; nf < 4; ++nf) {
        float g0 = gelu_f(acc1[mf][nf][0] * sc0 + of0);
        float g1 = gelu_f(acc1[mf][nf][1] * sc1 + of1);
        float g2 = gelu_f(acc1[mf][nf][2] * sc2 + of2);
        float g3 = gelu_f(acc1[mf][nf][3] * sc3 + of3);
        int col = 16 * nf + c;
        *(unsigned*)&Hs[col * 136 + kloc]     = packbf(g0, g1);
        *(unsigned*)&Hs[col * 136 + kloc + 2] = packbf(g2, g3);
      }
    }
    __syncthreads();

#pragma unroll
    for (int ks = 0; ks < 4; ++ks) {
      bf16x8 a20 = *(const bf16x8*)&w2f[(((4 * w + 0) * 32 + ch * 4 + ks) * 64 + l) * 8];
      bf16x8 a21 = *(const bf16x8*)&w2f[(((4 * w + 1) * 32 + ch * 4 + ks) * 64 + l) * 8];
      bf16x8 a22 = *(const bf16x8*)&w2f[(((4 * w + 2) * 32 + ch * 4 + ks) * 64 + l) * 8];
      bf16x8 a23 = *(const bf16x8*)&w2f[(((4 * w + 3) * 32 + ch * 4 + ks) * 64 + l) * 8];
      bf16x8 h0 = *(const bf16x8*)&Hs[(0  + c) * 136 + 32 * ks + 8 * kg];
      bf16x8 h1 = *(const bf16x8*)&Hs[(16 + c) * 136 + 32 * ks + 8 * kg];
      bf16x8 h2 = *(const bf16x8*)&Hs[(32 + c) * 136 + 32 * ks + 8 * kg];
      bf16x8 h3 = *(const bf16x8*)&Hs[(48 + c) * 136 + 32 * ks + 8 * kg];
      acc2[0][0] = __builtin_amdgcn_mfma_f32_16x16x32_bf16(a20, h0, acc2[0][0], 0, 0, 0);
      acc2[0][1] = __builtin_amdgcn_mfma_f32_16x16x32_bf16(a20, h1, acc2[0][1], 0, 0, 0);
      acc2[0][2] = __builtin_amdgcn_mfma_f32_16x16x32_bf16(a20, h2, acc2[0][2], 0, 0, 0);
      acc2[0][3] = __builtin_amdgcn_mfma_f32_16x16x32_bf16(a20, h3, acc2[0][3], 0, 0, 0);
      acc2[1][0] = __builtin_amdgcn_mfma_f32_16x16x32_bf16(a21, h0, acc2[1][0], 0, 0, 0);
      acc2[1][1] = __builtin_amdgcn_mfma_f32_16x16x32_bf16(a21, h1, acc2[1][1], 0, 0, 0);
      acc2[1][2] = __builtin_amdgcn_mfma_f32_16x16x32_bf16(a21, h2, acc2[1][2], 0, 0, 0);
      acc2[1][3] = __builtin_amdgcn_mfma_f32_16x16x32_bf16(a21, h3, acc2[1][3], 0, 0, 0);
      acc2[2][0] = __builtin_amdgcn_mfma_f32_16x16x32_bf16(a22, h0, acc2[2][0], 0, 0, 0);
      acc2[2][1] = __builtin_amdgcn_mfma_f32_16x16x32_bf16(a22, h1, acc2[2][1], 0, 0, 0);
      acc2[2][2] = __builtin_amdgcn_mfma_f32_16x16x32_bf16(a22, h2, acc2[2][2], 0, 0, 0);
      acc2[2][3] = __builtin_amdgcn_mfma_f32_16x16x32_bf16(a22, h3, acc2[2][3], 0, 0, 0);
      acc2[3][0] = __builtin_amdgcn_mfma_f32_16x16x32_bf16(a23, h0, acc2[3][0], 0, 0, 0);
      acc2[3][1] = __builtin_amdgcn_mfma_f32_16x16x32_bf16(a23, h1, acc2[3][1], 0, 0, 0);
      acc2[3][2] = __builtin_amdgcn_mfma_f32_16x16x32_bf16(a23, h2, acc2[3][2], 0, 0, 0);
      acc2[3][3] = __builtin_amdgcn_mfma_f32_16x16x32_bf16(a23, h3, acc2[3][3], 0, 0, 0);
    }
  }

#pragma unroll
  for (int mf = 0; mf < 4; ++mf) {
    int cob = 64 * w + 16 * mf + 4 * kg;
    float sc0 = cb2[cob + 0], sc1 = cb2[cob + 1], sc2 = cb2[cob + 2], sc3 = cb2[cob + 3];
    float of0 = cb2[C_ + cob + 0], of1 = cb2[C_ + cob + 1];
    float of2 = cb2[C_ + cob + 2], of3 = cb2[C_ + cob + 3];
#pragma unroll
    for (int nf = 0; nf < 4; ++nf) {
      int s = s0 + 16 * nf + c;
      int xi0 = (b * C_ + cob) * THW + s;
      out[xi0]            = xp[xi0]            + acc2[mf][nf][0] * sc0 + of0;
      out[xi0 + THW]      = xp[xi0 + THW]      + acc2[mf][nf][1] * sc1 + of1;
      out[xi0 + 2 * THW]  = xp[xi0 + 2 * THW]  + acc2[mf][nf][2] * sc2 + of2;
      out[xi0 + 3 * THW]  = xp[xi0 + 3 * THW]  + acc2[mf][nf][3] * sc3 + of3;
    }
  }
}

// ---------------- launch ----------------
extern "C" void kernel_launch(void* const* d_in, const int* in_sizes, int n_in,
                              void* d_out, int out_size, void* d_ws, size_t ws_size,
                              hipStream_t stream)
{
  const float* x    = (const float*)d_in[0];
  const float* n1g  = (const float*)d_in[1];
  const float* n1b  = (const float*)d_in[2];
  const float* n1m  = (const float*)d_in[3];
  const float* n1v  = (const float*)d_in[4];
  const float* qkvw = (const float*)d_in[5];
  const float* qbng = (const float*)d_in[6];
  const float* qbnb = (const float*)d_in[7];
  const float* qbnm = (const float*)d_in[8];
  const float* qbnv = (const float*)d_in[9];
  const float* projw= (const float*)d_in[10];
  const float* projb= (const float*)d_in[11];
  const float* n2g  = (const float*)d_in[12];
  const float* n2b  = (const float*)d_in[13];
  const float* n2m  = (const float*)d_in[14];
  const float* n2v  = (const float*)d_in[15];
  const float* fc1w = (const float*)d_in[16];
  const float* fc1b = (const float*)d_in[17];
  const float* b1g  = (const float*)d_in[18];
  const float* b1b  = (const float*)d_in[19];
  const float* b1m  = (const float*)d_in[20];
  const float* b1v  = (const float*)d_in[21];
  const float* fc2w = (const float*)d_in[22];
  const float* fc2b = (const float*)d_in[23];
  const float* b2g  = (const float*)d_in[24];
  const float* b2b  = (const float*)d_in[25];
  const float* b2m  = (const float*)d_in[26];
  const float* b2v  = (const float*)d_in[27];

  float* wsf   = (float*)d_ws;
  float* c_n1  = wsf;                       // 512
  float* c_qbn = wsf + 512;                 // 1536
  float* c_n2  = wsf + 2048;                // 512
  float* c_b1  = wsf + 2560;                // 2048
  float* c_b2  = wsf + 4608;                // 512
  unsigned short* w1f = (unsigned short*)(wsf + 5120);     // 262144 bf16
  unsigned short* w2f = (unsigned short*)(wsf + 136192);   // 262144 bf16
  unsigned short* pwf = (unsigned short*)(wsf + 267264);   // 65536 bf16
  unsigned short* wcf = (unsigned short*)(wsf + 300032);   // 1769472 bf16
  float* qw = wsf + 1184768;                // 4227072
  float* kw = qw + 4227072;
  float* vw = kw + 4227072;
  float* aw = vw + 4227072;                 // end: 18,093,056 floats = 72.4 MB

  // x-hat (bf16 NHWC) lives in d_out until proj_mfma overwrites it
  unsigned short* xt = (unsigned short*)d_out;

  bn_pre<<<1, 256, 0, stream>>>(n1g, n1b, n1m, n1v, c_n1, 256);
  bn_pre<<<3, 256, 0, stream>>>(qbng, qbnb, qbnm, qbnv, c_qbn, 768);
  bn_pre<<<1, 256, 0, stream>>>(n2g, n2b, n2m, n2v, c_n2, 256);
  bn_pre_bias<<<4, 256, 0, stream>>>(b1g, b1b, b1m, b1v, fc1b, c_b1, 1024);
  bn_pre_bias<<<1, 256, 0, stream>>>(b2g, b2b, b2m, b2v, fc2b, c_b2, 256);
  mk_frag<<<1024, 256, 0, stream>>>(fc1w, w1f, 1024, 256);
  mk_frag<<<1024, 256, 0, stream>>>(fc2w, w2f, 256, 1024);
  mk_frag<<<256, 256, 0, stream>>>(projw, pwf, 256, 256);
  mk_frag_conv<<<6912, 256, 0, stream>>>(qkvw, wcf);

  xhat_k<<<2176, 256, 0, stream>>>(x, c_n1, xt);

  dim3 gconv(258, 3);
  conv_mfma<<<gconv, 256, 0, stream>>>(xt, wcf, c_qbn, qw, kw, vw);
  attn_k<<<512, 256, 0, stream>>>(qw, kw, vw, aw);
  proj_mfma<<<2176, 256, 0, stream>>>(aw, pwf, projb, x, (float*)d_out);
  mlp_mfma<<<2176, 256, 0, stream>>>((const float*)d_out, w1f, w2f,
                                     c_n2, c_b1, c_b2, (float*)d_out);
}

// Round 4
// 1035.082 us; speedup vs baseline: 9.9378x; 1.4469x over previous
//
#include <hip/hip_runtime.h>
#include <math.h>

// ---------------- problem constants ----------------
#define B_   64
#define C_   256
#define T_   128
#define J_   17
#define THW  2176      // T_*J_
#define HC   43
#define WC   6
#define P_   258       // HC*WC
#define NH_  8
#define HD_  32
#define HID_ 1024
#define KCONV 2304     // 256*9
#define NKT_CONV 72    // 2304/32

typedef __attribute__((ext_vector_type(8))) short bf16x8;
typedef __attribute__((ext_vector_type(4))) float f32x4;

__device__ __forceinline__ unsigned f2b1(float x) {
  union { float f; unsigned u; } c; c.f = x;
  return (c.u + 0x7fffu + ((c.u >> 16) & 1u)) >> 16;   // RNE bf16
}
__device__ __forceinline__ unsigned packbf(float a, float b) {
  return f2b1(a) | (f2b1(b) << 16);
}
__device__ __forceinline__ float gelu_f(float v) {
  return 0.5f * v * (1.f + erff(v * 0.70710678118654752f));
}

// ---------------- precompute kernels ----------------
__global__ void bn_pre(const float* __restrict__ g, const float* __restrict__ b,
                       const float* __restrict__ m, const float* __restrict__ v,
                       float* __restrict__ o, int n)
{
  for (int i = blockIdx.x * blockDim.x + threadIdx.x; i < n; i += gridDim.x * blockDim.x) {
    float inv = g[i] / sqrtf(v[i] + 1e-5f);
    o[i]     = inv;
    o[n + i] = b[i] - m[i] * inv;
  }
}

__global__ void bn_pre_bias(const float* __restrict__ g, const float* __restrict__ b,
                            const float* __restrict__ m, const float* __restrict__ v,
                            const float* __restrict__ bias, float* __restrict__ o, int n)
{
  for (int i = blockIdx.x * blockDim.x + threadIdx.x; i < n; i += gridDim.x * blockDim.x) {
    float inv = g[i] / sqrtf(v[i] + 1e-5f);
    o[i]     = inv;
    o[n + i] = b[i] - m[i] * inv + bias[i] * inv;
  }
}

// weight (M,K) fp32 row-major -> bf16 MFMA A-fragments
__global__ void mk_frag(const float* __restrict__ w, unsigned short* __restrict__ wf,
                        int M, int K)
{
  int i = blockIdx.x * 256 + threadIdx.x;
  if (i >= M * K) return;
  int j = i & 7, l = (i >> 3) & 63;
  int rest = i >> 9;
  int nkt = K >> 5;
  int kt = rest % nkt, rt = rest / nkt;
  int row = 16 * rt + (l & 15);
  int k   = 32 * kt + 8 * (l >> 4) + j;
  wf[i] = (unsigned short)f2b1(w[row * K + k]);
}

// qkv conv weights (768,256,3,3) -> fragments, K reordered kernel-pos-major
__global__ void mk_frag_conv(const float* __restrict__ w, unsigned short* __restrict__ wf)
{
  int i = blockIdx.x * 256 + threadIdx.x;
  if (i >= 768 * KCONV) return;
  int j = i & 7, l = (i >> 3) & 63;
  int rest = i >> 9;
  int kt = rest % NKT_CONV, rt = rest / NKT_CONV;
  int row = 16 * rt + (l & 15);
  int k   = 32 * kt + 8 * (l >> 4) + j;
  int kp = k >> 8, ci = k & 255;
  wf[i] = (unsigned short)f2b1(w[row * KCONV + ci * 9 + kp]);
}

// ---------------- x-hat: bf16(bn1(x)) in NHWC (in d_out's dead space) ----------------
__global__ __launch_bounds__(256) void xhat_k(
    const float* __restrict__ x, const float* __restrict__ cn1,
    unsigned short* __restrict__ xt)
{
  __shared__ unsigned short Ux[64 * 264];
  const int blk = blockIdx.x;
  const int b = blk / 34;
  const int s0 = (blk - b * 34) * 64;
  const int tid = threadIdx.x;
  const int col = tid & 63, ofs = tid >> 6;
#pragma unroll 1
  for (int cp = ofs; cp < 128; cp += 4) {
    int ci0 = 2 * cp;
    float va = x[(b * C_ + ci0)     * THW + s0 + col] * cn1[ci0]     + cn1[C_ + ci0];
    float vb = x[(b * C_ + ci0 + 1) * THW + s0 + col] * cn1[ci0 + 1] + cn1[C_ + ci0 + 1];
    *(unsigned*)&Ux[col * 264 + ci0] = packbf(va, vb);
  }
  __syncthreads();
  const uint4* srcl = (const uint4*)&Ux[col * 264];
  uint4* dst = (uint4*)&xt[(size_t)(b * THW + s0 + col) * 256];
#pragma unroll
  for (int i = 0; i < 8; ++i) {
    int vi = ofs + 4 * i;
    dst[vi] = srcl[vi];
  }
}

// ---------------- conv qkv via MFMA: M=768 K=2304 N=16512; bf16 q/k/v out ----------
__global__ __launch_bounds__(256) void conv_mfma(
    const unsigned short* __restrict__ xt, const unsigned short* __restrict__ wcf,
    const float* __restrict__ cqbn,
    unsigned short* __restrict__ qo, unsigned short* __restrict__ ko,
    unsigned short* __restrict__ vo)
{
  __shared__ unsigned short U[64 * 264];
  const int tid = threadIdx.x;
  const int l = tid & 63, w = tid >> 6;
  const int c = l & 15, kg = l >> 4;
  const int col0 = blockIdx.x * 64;
  const int mb = blockIdx.y;

  const int gcol = col0 + l;
  const int b = gcol / P_, p = gcol - b * P_;
  const int oh = p / WC, ow = p - oh * WC;
  const unsigned short* xb = xt + (size_t)b * THW * 256;

  f32x4 acc[4][4];
#pragma unroll
  for (int mf = 0; mf < 4; ++mf)
#pragma unroll
    for (int nf = 0; nf < 4; ++nf)
      acc[mf][nf] = (f32x4){0.f, 0.f, 0.f, 0.f};

  for (int kp = 0; kp < 9; ++kp) {
    const int kh = kp / 3, kwp = kp - 3 * kh;
    const int ir = 3 * oh - 1 + kh, ic = 3 * ow - 1 + kwp;
    const bool valid = ((unsigned)ir < (unsigned)T_) && ((unsigned)ic < (unsigned)J_);
    __syncthreads();
    if (valid) {
      const uint4* src = (const uint4*)(xb + (size_t)(ir * J_ + ic) * 256);
#pragma unroll
      for (int i = 0; i < 8; ++i) {
        int vi = w + 4 * i;
        *(uint4*)&U[l * 264 + vi * 8] = src[vi];
      }
    } else {
      uint4 z = {0u, 0u, 0u, 0u};
#pragma unroll
      for (int i = 0; i < 8; ++i) {
        int vi = w + 4 * i;
        *(uint4*)&U[l * 264 + vi * 8] = z;
      }
    }
    __syncthreads();
#pragma unroll
    for (int ks = 0; ks < 8; ++ks) {
      const int kt = kp * 8 + ks;
      bf16x8 a0 = *(const bf16x8*)&wcf[(((mb * 16 + w * 4 + 0) * NKT_CONV + kt) * 64 + l) * 8];
      bf16x8 a1 = *(const bf16x8*)&wcf[(((mb * 16 + w * 4 + 1) * NKT_CONV + kt) * 64 + l) * 8];
      bf16x8 a2 = *(const bf16x8*)&wcf[(((mb * 16 + w * 4 + 2) * NKT_CONV + kt) * 64 + l) * 8];
      bf16x8 a3 = *(const bf16x8*)&wcf[(((mb * 16 + w * 4 + 3) * NKT_CONV + kt) * 64 + l) * 8];
      bf16x8 b0 = *(const bf16x8*)&U[(0  + c) * 264 + 32 * ks + 8 * kg];
      bf16x8 b1 = *(const bf16x8*)&U[(16 + c) * 264 + 32 * ks + 8 * kg];
      bf16x8 b2 = *(const bf16x8*)&U[(32 + c) * 264 + 32 * ks + 8 * kg];
      bf16x8 b3 = *(const bf16x8*)&U[(48 + c) * 264 + 32 * ks + 8 * kg];
      acc[0][0] = __builtin_amdgcn_mfma_f32_16x16x32_bf16(a0, b0, acc[0][0], 0, 0, 0);
      acc[0][1] = __builtin_amdgcn_mfma_f32_16x16x32_bf16(a0, b1, acc[0][1], 0, 0, 0);
      acc[0][2] = __builtin_amdgcn_mfma_f32_16x16x32_bf16(a0, b2, acc[0][2], 0, 0, 0);
      acc[0][3] = __builtin_amdgcn_mfma_f32_16x16x32_bf16(a0, b3, acc[0][3], 0, 0, 0);
      acc[1][0] = __builtin_amdgcn_mfma_f32_16x16x32_bf16(a1, b0, acc[1][0], 0, 0, 0);
      acc[1][1] = __builtin_amdgcn_mfma_f32_16x16x32_bf16(a1, b1, acc[1][1], 0, 0, 0);
      acc[1][2] = __builtin_amdgcn_mfma_f32_16x16x32_bf16(a1, b2, acc[1][2], 0, 0, 0);
      acc[1][3] = __builtin_amdgcn_mfma_f32_16x16x32_bf16(a1, b3, acc[1][3], 0, 0, 0);
      acc[2][0] = __builtin_amdgcn_mfma_f32_16x16x32_bf16(a2, b0, acc[2][0], 0, 0, 0);
      acc[2][1] = __builtin_amdgcn_mfma_f32_16x16x32_bf16(a2, b1, acc[2][1], 0, 0, 0);
      acc[2][2] = __builtin_amdgcn_mfma_f32_16x16x32_bf16(a2, b2, acc[2][2], 0, 0, 0);
      acc[2][3] = __builtin_amdgcn_mfma_f32_16x16x32_bf16(a2, b3, acc[2][3], 0, 0, 0);
      acc[3][0] = __builtin_amdgcn_mfma_f32_16x16x32_bf16(a3, b0, acc[3][0], 0, 0, 0);
      acc[3][1] = __builtin_amdgcn_mfma_f32_16x16x32_bf16(a3, b1, acc[3][1], 0, 0, 0);
      acc[3][2] = __builtin_amdgcn_mfma_f32_16x16x32_bf16(a3, b2, acc[3][2], 0, 0, 0);
      acc[3][3] = __builtin_amdgcn_mfma_f32_16x16x32_bf16(a3, b3, acc[3][3], 0, 0, 0);
    }
  }

  // epilogue: qbn + gelu + bf16 scatter to q/k/v (which = mb, uniform)
#pragma unroll
  for (int nf = 0; nf < 4; ++nf) {
    int gcol2 = col0 + 16 * nf + c;
    int b2 = gcol2 / P_, p2 = gcol2 - b2 * P_;
#pragma unroll
    for (int mf = 0; mf < 4; ++mf) {
      int col = w * 64 + 16 * mf + 4 * kg;
#pragma unroll
      for (int jj = 0; jj < 4; ++jj) {
        int rr = col + jj;
        int co = mb * 256 + rr;
        float vv = acc[mf][nf][jj] * cqbn[co] + cqbn[768 + co];
        float ge = gelu_f(vv);
        int head = rr >> 5, d = rr & 31;
        int idx = ((b2 * NH_ + head) * P_ + p2) * HD_ + d;
        if (mb == 0)      qo[idx] = (unsigned short)f2b1(ge * 0.176776695296636881f);
        else if (mb == 1) ko[idx] = (unsigned short)f2b1(ge);
        else              vo[idx] = (unsigned short)f2b1(ge);
      }
    }
  }
}

// ---------------- attention via MFMA: one block per (b,h), 4 waves ----------------
// S = Q K^T (17 k-tiles, K=32 = one k-step), softmax in-register, P->LDS, O = P V
__global__ __launch_bounds__(256) void attn_mfma(
    const unsigned short* __restrict__ q, const unsigned short* __restrict__ k,
    const unsigned short* __restrict__ v, float* __restrict__ o)
{
  __shared__ unsigned short Kl[272 * 40];      // [krow][d], stride 40
  __shared__ unsigned short Vt[32 * 296];      // [d][krow], stride 296
  __shared__ unsigned short Pl[4][16 * 296];   // per-wave [qrow][krow], stride 296
  const int bh = blockIdx.x;
  const int tid = threadIdx.x, l = tid & 63, w = tid >> 6;
  const int c = l & 15, g = l >> 4;
  const unsigned short* kb_ = k + (size_t)bh * P_ * HD_;
  const unsigned short* vb_ = v + (size_t)bh * P_ * HD_;
  const unsigned short* qb_ = q + (size_t)bh * P_ * HD_;

  // ---- stage K (row-major) and V^T into LDS ----
  for (int e = tid; e < 1032; e += 256) {       // 258*32/8
    int kr = e >> 2, d0 = (e & 3) * 8;
    uint4 val = *(const uint4*)(kb_ + kr * 32 + d0);
    *(uint4*)&Kl[kr * 40 + d0] = val;
    uint4 vv = *(const uint4*)(vb_ + kr * 32 + d0);
    unsigned short tmp[8];
    *(uint4*)tmp = vv;
#pragma unroll
    for (int i = 0; i < 8; ++i) Vt[(d0 + i) * 296 + kr] = tmp[i];
  }
  for (int e = tid; e < 14 * 32; e += 256)      // zero K pad rows 258..271
    Kl[(258 + (e >> 5)) * 40 + (e & 31)] = 0;
  for (int e = tid; e < 32 * 32; e += 256)      // zero V^T pad cols 258..289
    Vt[(e >> 5) * 296 + 258 + (e & 31)] = 0;
  __syncthreads();

  for (int qt = w; qt < 17; qt += 4) {
    int qrow = qt * 16 + c; if (qrow > 257) qrow = 257;
    bf16x8 aq = *(const bf16x8*)(qb_ + qrow * 32 + 8 * g);

    f32x4 st[17];
#pragma unroll
    for (int kt = 0; kt < 17; ++kt) {
      bf16x8 bk = *(const bf16x8*)&Kl[(kt * 16 + c) * 40 + 8 * g];
      st[kt] = __builtin_amdgcn_mfma_f32_16x16x32_bf16(aq, bk, (f32x4){0.f,0.f,0.f,0.f}, 0, 0, 0);
    }
    if (c >= 2) st[16] = (f32x4){-1e30f, -1e30f, -1e30f, -1e30f};

    // softmax per q-row (row = 4*g + r, cols spread over 16 lanes x 17 tiles)
#pragma unroll
    for (int r = 0; r < 4; ++r) {
      float mm = st[0][r];
#pragma unroll
      for (int kt = 1; kt < 17; ++kt) mm = fmaxf(mm, st[kt][r]);
      mm = fmaxf(mm, __shfl_xor(mm, 1));
      mm = fmaxf(mm, __shfl_xor(mm, 2));
      mm = fmaxf(mm, __shfl_xor(mm, 4));
      mm = fmaxf(mm, __shfl_xor(mm, 8));
      float ss = 0.f;
#pragma unroll
      for (int kt = 0; kt < 17; ++kt) {
        float p = __expf(st[kt][r] - mm);
        st[kt][r] = p;
        ss += p;
      }
      ss += __shfl_xor(ss, 1);
      ss += __shfl_xor(ss, 2);
      ss += __shfl_xor(ss, 4);
      ss += __shfl_xor(ss, 8);
      float rinv = 1.f / ss;
#pragma unroll
      for (int kt = 0; kt < 17; ++kt) st[kt][r] *= rinv;
    }

    // pack P to LDS (bf16), zero pad cols 272..287
#pragma unroll
    for (int r = 0; r < 4; ++r) {
      int prow = (4 * g + r) * 296;
#pragma unroll
      for (int kt = 0; kt < 17; ++kt)
        Pl[w][prow + kt * 16 + c] = (unsigned short)f2b1(st[kt][r]);
      Pl[w][prow + 272 + c] = 0;
    }
    __builtin_amdgcn_wave_barrier();

    // O = P V : 9 k-steps x 2 d-tiles
    f32x4 oc0 = (f32x4){0.f,0.f,0.f,0.f}, oc1 = (f32x4){0.f,0.f,0.f,0.f};
#pragma unroll
    for (int ks = 0; ks < 9; ++ks) {
      bf16x8 ap  = *(const bf16x8*)&Pl[w][c * 296 + ks * 32 + 8 * g];
      bf16x8 bv0 = *(const bf16x8*)&Vt[c * 296 + ks * 32 + 8 * g];
      bf16x8 bv1 = *(const bf16x8*)&Vt[(c + 16) * 296 + ks * 32 + 8 * g];
      oc0 = __builtin_amdgcn_mfma_f32_16x16x32_bf16(ap, bv0, oc0, 0, 0, 0);
      oc1 = __builtin_amdgcn_mfma_f32_16x16x32_bf16(ap, bv1, oc1, 0, 0, 0);
    }

#pragma unroll
    for (int r = 0; r < 4; ++r) {
      int row = qt * 16 + 4 * g + r;
      if (row < P_) {
        float* ob = o + ((size_t)bh * P_ + row) * HD_;
        ob[c]      = oc0[r];
        ob[16 + c] = oc1[r];
      }
    }
    __builtin_amdgcn_wave_barrier();
  }
}

// ---------------- bilinear resize + 1x1 proj (MFMA) + residual -> x' in d_out ------
__global__ __launch_bounds__(256) void proj_mfma(
    const float* __restrict__ ao, const unsigned short* __restrict__ pwf,
    const float* __restrict__ projb, const float* __restrict__ x,
    float* __restrict__ out)
{
  __shared__ unsigned short R[64 * 264];
  __shared__ float cwS[64][4];
  __shared__ int   cixS[64][4];
  const int tid = threadIdx.x;
  const int l = tid & 63, w = tid >> 6;
  const int c = l & 15, kg = l >> 4;
  const int blk = blockIdx.x;
  const int b = blk / 34;
  const int s0 = (blk - b * 34) * 64;

  if (tid < 64) {
    int s = s0 + tid;
    int t = s / J_, j = s - t * J_;
    float ft = fmaxf((t + 0.5f) * ((float)HC / (float)T_) - 0.5f, 0.f);
    float fj = fmaxf((j + 0.5f) * ((float)WC / (float)J_) - 0.5f, 0.f);
    int i0 = (int)ft; if (i0 > HC - 1) i0 = HC - 1;
    int j0 = (int)fj; if (j0 > WC - 1) j0 = WC - 1;
    int i1 = min(i0 + 1, HC - 1);
    int j1 = min(j0 + 1, WC - 1);
    float wt_ = ft - (float)i0, wj_ = fj - (float)j0;
    cixS[tid][0] = i0 * WC + j0; cixS[tid][1] = i0 * WC + j1;
    cixS[tid][2] = i1 * WC + j0; cixS[tid][3] = i1 * WC + j1;
    cwS[tid][0] = (1.f - wt_) * (1.f - wj_); cwS[tid][1] = (1.f - wt_) * wj_;
    cwS[tid][2] = wt_ * (1.f - wj_);         cwS[tid][3] = wt_ * wj_;
  }
  __syncthreads();

  for (int e = tid; e < 64 * 128; e += 256) {
    int cp = e >> 6, col = e & 63;
    int ci0 = 2 * cp;
    int head = ci0 >> 5, d = ci0 & 31;
    const float* A = ao + (size_t)(b * NH_ + head) * (P_ * HD_) + d;
    float w0 = cwS[col][0], w1 = cwS[col][1], w2 = cwS[col][2], w3 = cwS[col][3];
    int i0 = cixS[col][0] * HD_, i1 = cixS[col][1] * HD_;
    int i2 = cixS[col][2] * HD_, i3 = cixS[col][3] * HD_;
    float v0 = w0 * A[i0]     + w1 * A[i1]     + w2 * A[i2]     + w3 * A[i3];
    float v1 = w0 * A[i0 + 1] + w1 * A[i1 + 1] + w2 * A[i2 + 1] + w3 * A[i3 + 1];
    *(unsigned*)&R[col * 264 + ci0] = packbf(v0, v1);
  }
  __syncthreads();

  f32x4 acc[4][4];
#pragma unroll
  for (int mf = 0; mf < 4; ++mf)
#pragma unroll
    for (int nf = 0; nf < 4; ++nf)
      acc[mf][nf] = (f32x4){0.f, 0.f, 0.f, 0.f};

#pragma unroll
  for (int ks = 0; ks < 8; ++ks) {
    bf16x8 a0 = *(const bf16x8*)&pwf[(((w * 4 + 0) * 8 + ks) * 64 + l) * 8];
    bf16x8 a1 = *(const bf16x8*)&pwf[(((w * 4 + 1) * 8 + ks) * 64 + l) * 8];
    bf16x8 a2 = *(const bf16x8*)&pwf[(((w * 4 + 2) * 8 + ks) * 64 + l) * 8];
    bf16x8 a3 = *(const bf16x8*)&pwf[(((w * 4 + 3) * 8 + ks) * 64 + l) * 8];
    bf16x8 b0 = *(const bf16x8*)&R[(0  + c) * 264 + 32 * ks + 8 * kg];
    bf16x8 b1 = *(const bf16x8*)&R[(16 + c) * 264 + 32 * ks + 8 * kg];
    bf16x8 b2 = *(const bf16x8*)&R[(32 + c) * 264 + 32 * ks + 8 * kg];
    bf16x8 b3 = *(const bf16x8*)&R[(48 + c) * 264 + 32 * ks + 8 * kg];
    acc[0][0] = __builtin_amdgcn_mfma_f32_16x16x32_bf16(a0, b0, acc[0][0], 0, 0, 0);
    acc[0][1] = __builtin_amdgcn_mfma_f32_16x16x32_bf16(a0, b1, acc[0][1], 0, 0, 0);
    acc[0][2] = __builtin_amdgcn_mfma_f32_16x16x32_bf16(a0, b2, acc[0][2], 0, 0, 0);
    acc[0][3] = __builtin_amdgcn_mfma_f32_16x16x32_bf16(a0, b3, acc[0][3], 0, 0, 0);
    acc[1][0] = __builtin_amdgcn_mfma_f32_16x16x32_bf16(a1, b0, acc[1][0], 0, 0, 0);
    acc[1][1] = __builtin_amdgcn_mfma_f32_16x16x32_bf16(a1, b1, acc[1][1], 0, 0, 0);
    acc[1][2] = __builtin_amdgcn_mfma_f32_16x16x32_bf16(a1, b2, acc[1][2], 0, 0, 0);
    acc[1][3] = __builtin_amdgcn_mfma_f32_16x16x32_bf16(a1, b3, acc[1][3], 0, 0, 0);
    acc[2][0] = __builtin_amdgcn_mfma_f32_16x16x32_bf16(a2, b0, acc[2][0], 0, 0, 0);
    acc[2][1] = __builtin_amdgcn_mfma_f32_16x16x32_bf16(a2, b1, acc[2][1], 0, 0, 0);
    acc[2][2] = __builtin_amdgcn_mfma_f32_16x16x32_bf16(a2, b2, acc[2][2], 0, 0, 0);
    acc[2][3] = __builtin_amdgcn_mfma_f32_16x16x32_bf16(a2, b3, acc[2][3], 0, 0, 0);
    acc[3][0] = __builtin_amdgcn_mfma_f32_16x16x32_bf16(a3, b0, acc[3][0], 0, 0, 0);
    acc[3][1] = __builtin_amdgcn_mfma_f32_16x16x32_bf16(a3, b1, acc[3][1], 0, 0, 0);
    acc[3][2] = __builtin_amdgcn_mfma_f32_16x16x32_bf16(a3, b2, acc[3][2], 0, 0, 0);
    acc[3][3] = __builtin_amdgcn_mfma_f32_16x16x32_bf16(a3, b3, acc[3][3], 0, 0, 0);
  }

#pragma unroll
  for (int mf = 0; mf < 4; ++mf) {
    int cob = w * 64 + 16 * mf + 4 * kg;
#pragma unroll
    for (int nf = 0; nf < 4; ++nf) {
      int s = s0 + 16 * nf + c;
#pragma unroll
      for (int jj = 0; jj < 4; ++jj) {
        int co = cob + jj;
        int xi = (b * C_ + co) * THW + s;
        out[xi] = x[xi] + projb[co] + acc[mf][nf][jj];
      }
    }
  }
}

// ---------------- fused MLP via bf16 MFMA ----------------
__global__ __launch_bounds__(256) void mlp_mfma(
    const float* __restrict__ xp,
    const unsigned short* __restrict__ w1f, const unsigned short* __restrict__ w2f,
    const float* __restrict__ cn2, const float* __restrict__ cb1,
    const float* __restrict__ cb2, float* __restrict__ out)
{
  __shared__ unsigned short U[64 * 264];
  __shared__ unsigned short Hs[64 * 136];
  const int tid = threadIdx.x;
  const int l   = tid & 63, w = tid >> 6;
  const int c   = l & 15, kg = l >> 4;
  const int blk = blockIdx.x;
  const int b   = blk / 34;
  const int s0  = (blk - b * 34) * 64;

  {
    const int col = tid & 63;
    const int ofs = tid >> 6;
#pragma unroll 1
    for (int cp = ofs; cp < 128; cp += 4) {
      int ci0 = 2 * cp;
      float sa = cn2[ci0],     oa = cn2[C_ + ci0];
      float sb = cn2[ci0 + 1], ob = cn2[C_ + ci0 + 1];
      float va = xp[(b * C_ + ci0) * THW + s0 + col] * sa + oa;
      float vb = xp[(b * C_ + ci0 + 1) * THW + s0 + col] * sb + ob;
      *(unsigned*)&U[col * 264 + ci0] = packbf(va, vb);
    }
  }
  __syncthreads();

  f32x4 acc2[4][4];
#pragma unroll
  for (int mf = 0; mf < 4; ++mf)
#pragma unroll
    for (int nf = 0; nf < 4; ++nf)
      acc2[mf][nf] = (f32x4){0.f, 0.f, 0.f, 0.f};

  for (int ch = 0; ch < 8; ++ch) {
    f32x4 acc1[2][4];
#pragma unroll
    for (int mf = 0; mf < 2; ++mf)
#pragma unroll
      for (int nf = 0; nf < 4; ++nf)
        acc1[mf][nf] = (f32x4){0.f, 0.f, 0.f, 0.f};

#pragma unroll
    for (int ks = 0; ks < 8; ++ks) {
      bf16x8 a0 = *(const bf16x8*)&w1f[(((ch * 8 + 2 * w + 0) * 8 + ks) * 64 + l) * 8];
      bf16x8 a1 = *(const bf16x8*)&w1f[(((ch * 8 + 2 * w + 1) * 8 + ks) * 64 + l) * 8];
      bf16x8 bf0 = *(const bf16x8*)&U[(0  + c) * 264 + 32 * ks + 8 * kg];
      bf16x8 bf1 = *(const bf16x8*)&U[(16 + c) * 264 + 32 * ks + 8 * kg];
      bf16x8 bf2 = *(const bf16x8*)&U[(32 + c) * 264 + 32 * ks + 8 * kg];
      bf16x8 bf3 = *(const bf16x8*)&U[(48 + c) * 264 + 32 * ks + 8 * kg];
      acc1[0][0] = __builtin_amdgcn_mfma_f32_16x16x32_bf16(a0, bf0, acc1[0][0], 0, 0, 0);
      acc1[0][1] = __builtin_amdgcn_mfma_f32_16x16x32_bf16(a0, bf1, acc1[0][1], 0, 0, 0);
      acc1[0][2] = __builtin_amdgcn_mfma_f32_16x16x32_bf16(a0, bf2, acc1[0][2], 0, 0, 0);
      acc1[0][3] = __builtin_amdgcn_mfma_f32_16x16x32_bf16(a0, bf3, acc1[0][3], 0, 0, 0);
      acc1[1][0] = __builtin_amdgcn_mfma_f32_16x16x32_bf16(a1, bf0, acc1[1][0], 0, 0, 0);
      acc1[1][1] = __builtin_amdgcn_mfma_f32_16x16x32_bf16(a1, bf1, acc1[1][1], 0, 0, 0);
      acc1[1][2] = __builtin_amdgcn_mfma_f32_16x16x32_bf16(a1, bf2, acc1[1][2], 0, 0, 0);
      acc1[1][3] = __builtin_amdgcn_mfma_f32_16x16x32_bf16(a1, bf3, acc1[1][3], 0, 0, 0);
    }

    __syncthreads();

#pragma unroll
    for (int mf = 0; mf < 2; ++mf) {
      int hbase = ch * 128 + 32 * w + 16 * mf + 4 * kg;
      float sc0 = cb1[hbase + 0], sc1 = cb1[hbase + 1], sc2 = cb1[hbase + 2], sc3 = cb1[hbase + 3];
      float of0 = cb1[HID_ + hbase + 0], of1 = cb1[HID_ + hbase + 1];
      float of2 = cb1[HID_ + hbase + 2], of3 = cb1[HID_ + hbase + 3];
      int kloc = 32 * w + 16 * mf + 4 * kg;
#pragma unroll
      for (int nf = 0; nf < 4; ++nf) {
        float g0 = gelu_f(acc1[mf][nf][0] * sc0 + of0);
        float g1 = gelu_f(acc1[mf][nf][1] * sc1 + of1);
        float g2 = gelu_f(acc1[mf][nf][2] * sc2 + of2);
        float g3 = gelu_f(acc1[mf][nf][3] * sc3 + of3);
        int col = 16 * nf + c;
        *(unsigned*)&Hs[col * 136 + kloc]     = packbf(g0, g1);
        *(unsigned*)&Hs[col * 136 + kloc + 2] = packbf(g2, g3);
      }
    }
    __syncthreads();

#pragma unroll
    for (int ks = 0; ks < 4; ++ks) {
      bf16x8 a20 = *(const bf16x8*)&w2f[(((4 * w + 0) * 32 + ch * 4 + ks) * 64 + l) * 8];
      bf16x8 a21 = *(const bf16x8*)&w2f[(((4 * w + 1) * 32 + ch * 4 + ks) * 64 + l) * 8];
      bf16x8 a22 = *(const bf16x8*)&w2f[(((4 * w + 2) * 32 + ch * 4 + ks) * 64 + l) * 8];
      bf16x8 a23 = *(const bf16x8*)&w2f[(((4 * w + 3) * 32 + ch * 4 + ks) * 64 + l) * 8];
      bf16x8 h0 = *(const bf16x8*)&Hs[(0  + c) * 136 + 32 * ks + 8 * kg];
      bf16x8 h1 = *(const bf16x8*)&Hs[(16 + c) * 136 + 32 * ks + 8 * kg];
      bf16x8 h2 = *(const bf16x8*)&Hs[(32 + c) * 136 + 32 * ks + 8 * kg];
      bf16x8 h3 = *(const bf16x8*)&Hs[(48 + c) * 136 + 32 * ks + 8 * kg];
      acc2[0][0] = __builtin_amdgcn_mfma_f32_16x16x32_bf16(a20, h0, acc2[0][0], 0, 0, 0);
      acc2[0][1] = __builtin_amdgcn_mfma_f32_16x16x32_bf16(a20, h1, acc2[0][1], 0, 0, 0);
      acc2[0][2] = __builtin_amdgcn_mfma_f32_16x16x32_bf16(a20, h2, acc2[0][2], 0, 0, 0);
      acc2[0][3] = __builtin_amdgcn_mfma_f32_16x16x32_bf16(a20, h3, acc2[0][3], 0, 0, 0);
      acc2[1][0] = __builtin_amdgcn_mfma_f32_16x16x32_bf16(a21, h0, acc2[1][0], 0, 0, 0);
      acc2[1][1] = __builtin_amdgcn_mfma_f32_16x16x32_bf16(a21, h1, acc2[1][1], 0, 0, 0);
      acc2[1][2] = __builtin_amdgcn_mfma_f32_16x16x32_bf16(a21, h2, acc2[1][2], 0, 0, 0);
      acc2[1][3] = __builtin_amdgcn_mfma_f32_16x16x32_bf16(a21, h3, acc2[1][3], 0, 0, 0);
      acc2[2][0] = __builtin_amdgcn_mfma_f32_16x16x32_bf16(a22, h0, acc2[2][0], 0, 0, 0);
      acc2[2][1] = __builtin_amdgcn_mfma_f32_16x16x32_bf16(a22, h1, acc2[2][1], 0, 0, 0);
      acc2[2][2] = __builtin_amdgcn_mfma_f32_16x16x32_bf16(a22, h2, acc2[2][2], 0, 0, 0);
      acc2[2][3] = __builtin_amdgcn_mfma_f32_16x16x32_bf16(a22, h3, acc2[2][3], 0, 0, 0);
      acc2[3][0] = __builtin_amdgcn_mfma_f32_16x16x32_bf16(a23, h0, acc2[3][0], 0, 0, 0);
      acc2[3][1] = __builtin_amdgcn_mfma_f32_16x16x32_bf16(a23, h1, acc2[3][1], 0, 0, 0);
      acc2[3][2] = __builtin_amdgcn_mfma_f32_16x16x32_bf16(a23, h2, acc2[3][2], 0, 0, 0);
      acc2[3][3] = __builtin_amdgcn_mfma_f32_16x16x32_bf16(a23, h3, acc2[3][3], 0, 0, 0);
    }
  }

#pragma unroll
  for (int mf = 0; mf < 4; ++mf) {
    int cob = 64 * w + 16 * mf + 4 * kg;
    float sc0 = cb2[cob + 0], sc1 = cb2[cob + 1], sc2 = cb2[cob + 2], sc3 = cb2[cob + 3];
    float of0 = cb2[C_ + cob + 0], of1 = cb2[C_ + cob + 1];
    float of2 = cb2[C_ + cob + 2], of3 = cb2[C_ + cob + 3];
#pragma unroll
    for (int nf = 0; nf < 4; ++nf) {
      int s = s0 + 16 * nf + c;
      int xi0 = (b * C_ + cob) * THW + s;
      out[xi0]            = xp[xi0]            + acc2[mf][nf][0] * sc0 + of0;
      out[xi0 + THW]      = xp[xi0 + THW]      + acc2[mf][nf][1] * sc1 + of1;
      out[xi0 + 2 * THW]  = xp[xi0 + 2 * THW]  + acc2[mf][nf][2] * sc2 + of2;
      out[xi0 + 3 * THW]  = xp[xi0 + 3 * THW]  + acc2[mf][nf][3] * sc3 + of3;
    }
  }
}

// ---------------- launch ----------------
extern "C" void kernel_launch(void* const* d_in, const int* in_sizes, int n_in,
                              void* d_out, int out_size, void* d_ws, size_t ws_size,
                              hipStream_t stream)
{
  const float* x    = (const float*)d_in[0];
  const float* n1g  = (const float*)d_in[1];
  const float* n1b  = (const float*)d_in[2];
  const float* n1m  = (const float*)d_in[3];
  const float* n1v  = (const float*)d_in[4];
  const float* qkvw = (const float*)d_in[5];
  const float* qbng = (const float*)d_in[6];
  const float* qbnb = (const float*)d_in[7];
  const float* qbnm = (const float*)d_in[8];
  const float* qbnv = (const float*)d_in[9];
  const float* projw= (const float*)d_in[10];
  const float* projb= (const float*)d_in[11];
  const float* n2g  = (const float*)d_in[12];
  const float* n2b  = (const float*)d_in[13];
  const float* n2m  = (const float*)d_in[14];
  const float* n2v  = (const float*)d_in[15];
  const float* fc1w = (const float*)d_in[16];
  const float* fc1b = (const float*)d_in[17];
  const float* b1g  = (const float*)d_in[18];
  const float* b1b  = (const float*)d_in[19];
  const float* b1m  = (const float*)d_in[20];
  const float* b1v  = (const float*)d_in[21];
  const float* fc2w = (const float*)d_in[22];
  const float* fc2b = (const float*)d_in[23];
  const float* b2g  = (const float*)d_in[24];
  const float* b2b  = (const float*)d_in[25];
  const float* b2m  = (const float*)d_in[26];
  const float* b2v  = (const float*)d_in[27];

  float* wsf   = (float*)d_ws;
  float* c_n1  = wsf;                       // 512
  float* c_qbn = wsf + 512;                 // 1536
  float* c_n2  = wsf + 2048;                // 512
  float* c_b1  = wsf + 2560;                // 2048
  float* c_b2  = wsf + 4608;                // 512
  unsigned short* w1f = (unsigned short*)(wsf + 5120);     // 262144 bf16
  unsigned short* w2f = (unsigned short*)(wsf + 136192);   // 262144 bf16
  unsigned short* pwf = (unsigned short*)(wsf + 267264);   // 65536 bf16
  unsigned short* wcf = (unsigned short*)(wsf + 300032);   // 1769472 bf16
  unsigned short* qb16 = (unsigned short*)(wsf + 1184768); // 4227072 bf16
  unsigned short* kb16 = qb16 + 4227072;
  unsigned short* vb16 = kb16 + 4227072;
  float* aw = (float*)(vb16 + 4227072);     // 4227072 f32; end ~47 MB

  unsigned short* xt = (unsigned short*)d_out;   // x-hat lives in d_out until proj

  bn_pre<<<1, 256, 0, stream>>>(n1g, n1b, n1m, n1v, c_n1, 256);
  bn_pre<<<3, 256, 0, stream>>>(qbng, qbnb, qbnm, qbnv, c_qbn, 768);
  bn_pre<<<1, 256, 0, stream>>>(n2g, n2b, n2m, n2v, c_n2, 256);
  bn_pre_bias<<<4, 256, 0, stream>>>(b1g, b1b, b1m, b1v, fc1b, c_b1, 1024);
  bn_pre_bias<<<1, 256, 0, stream>>>(b2g, b2b, b2m, b2v, fc2b, c_b2, 256);
  mk_frag<<<1024, 256, 0, stream>>>(fc1w, w1f, 1024, 256);
  mk_frag<<<1024, 256, 0, stream>>>(fc2w, w2f, 256, 1024);
  mk_frag<<<256, 256, 0, stream>>>(projw, pwf, 256, 256);
  mk_frag_conv<<<6912, 256, 0, stream>>>(qkvw, wcf);

  xhat_k<<<2176, 256, 0, stream>>>(x, c_n1, xt);

  dim3 gconv(258, 3);
  conv_mfma<<<gconv, 256, 0, stream>>>(xt, wcf, c_qbn, qb16, kb16, vb16);
  attn_mfma<<<512, 256, 0, stream>>>(qb16, kb16, vb16, aw);
  proj_mfma<<<2176, 256, 0, stream>>>(aw, pwf, projb, x, (float*)d_out);
  mlp_mfma<<<2176, 256, 0, stream>>>((const float*)d_out, w1f, w2f,
                                     c_n2, c_b1, c_b2, (float*)d_out);
}